// Round 9
// baseline (422.330 us; speedup 1.0000x reference)
//
#include <hip/hip_runtime.h>
#include <math.h>

#define NNODES 50000
#define NEDGES 800000
#define DIN 256
#define DHID 128

typedef __attribute__((ext_vector_type(8))) short short8;
typedef __attribute__((ext_vector_type(4))) float f32x4;
typedef __attribute__((ext_vector_type(2))) float f32x2;

__device__ __forceinline__ unsigned short f2bf(float f) {
    unsigned u = __builtin_bit_cast(unsigned, f);
    u += 0x7fffu + ((u >> 16) & 1u);  // RNE
    return (unsigned short)(u >> 16);
}
__device__ __forceinline__ float bf2f(unsigned short s) {
    return __builtin_bit_cast(float, (unsigned)s << 16);
}
__device__ __forceinline__ unsigned packbf(float a, float b) {
    return (unsigned)f2bf(a) | ((unsigned)f2bf(b) << 16);
}
// DPP helpers: full-rate VALU cross-lane (no LDS latency)
__device__ __forceinline__ float dpp_xor1(float x) {  // quad_perm [1,0,3,2]
    return __builtin_bit_cast(float, __builtin_amdgcn_update_dpp(0, __builtin_bit_cast(int, x), 0xB1, 0xF, 0xF, true));
}
__device__ __forceinline__ float dpp_xor8(float x) {  // row_ror:8 (== xor8 in 16-lane row)
    return __builtin_bit_cast(float, __builtin_amdgcn_update_dpp(0, __builtin_bit_cast(int, x), 0x128, 0xF, 0xF, true));
}

// ---------------- CSR build ----------------
__global__ __launch_bounds__(256) void k_hist(const int* __restrict__ dst, int* __restrict__ counts) {
    int e = blockIdx.x * 256 + threadIdx.x;
    if (e < NEDGES) atomicAdd(&counts[dst[e]], 1);
}

__global__ __launch_bounds__(256) void k_scan_block(const int* __restrict__ in, int* __restrict__ out,
                                                    int* __restrict__ partials, int n) {
    __shared__ int sh[256];
    int tid = threadIdx.x;
    int i = blockIdx.x * 256 + tid;
    int vv = (i < n) ? in[i] : 0;
    sh[tid] = vv;
    __syncthreads();
    for (int off = 1; off < 256; off <<= 1) {
        int t = (tid >= off) ? sh[tid - off] : 0;
        __syncthreads();
        sh[tid] += t;
        __syncthreads();
    }
    if (i < n) out[i] = sh[tid];
    if (tid == 255) partials[blockIdx.x] = sh[255];
}

// merged: every block locally scans the (<=256) partials, then applies its prefix
__global__ __launch_bounds__(256) void k_apply2(const int* __restrict__ partials, int* __restrict__ row_ptr, int n,
                                                int nb) {
    __shared__ int sh[256];
    int tid = threadIdx.x;
    int vv = (tid < nb) ? partials[tid] : 0;
    sh[tid] = vv;
    __syncthreads();
    for (int off = 1; off < 256; off <<= 1) {
        int t = (tid >= off) ? sh[tid - off] : 0;
        __syncthreads();
        sh[tid] += t;
        __syncthreads();
    }
    int i = blockIdx.x * 256 + tid;
    if (i < n) {
        int add = blockIdx.x ? sh[blockIdx.x - 1] : 0;
        row_ptr[i + 1] += add;
    }
    if (i == 0) row_ptr[0] = 0;
}

// dst-sorted (src, ea) pairs; fill holds degrees (from hist), consumed by atomicSub
__global__ __launch_bounds__(256) void k_scatter(const int* __restrict__ src, const int* __restrict__ dst,
                                                 const float* __restrict__ ea, const int* __restrict__ row_ptr,
                                                 int* __restrict__ fill, int2* __restrict__ esrc) {
    int e = blockIdx.x * 256 + threadIdx.x;
    if (e < NEDGES) {
        int d = dst[e];
        int old = atomicSub(&fill[d], 1);
        int pos = row_ptr[d] + old - 1;
        esrc[pos] = make_int2(src[e], __float_as_int(ea[e]));
    }
}

// ---------------- weight prep: transpose + bf16 cast (merged) ----------------
__global__ __launch_bounds__(256) void prep_w(const float* __restrict__ Wi, const float* __restrict__ Wq,
                                              const float* __restrict__ Wk, const float* __restrict__ Wv,
                                              const float* __restrict__ Ws, unsigned short* __restrict__ Wit,
                                              unsigned short* __restrict__ Wt3) {
    int idx = blockIdx.x * 256 + threadIdx.x;
    if (idx < DHID * DIN) {
        int n = idx >> 8, kk = idx & 255;
        Wit[idx] = f2bf(Wi[kk * DHID + n]);
    }
    int idx2 = idx - DHID * DIN;
    if (idx2 >= 0 && idx2 < 3 * 512 * DHID) {
        int l = idx2 / (512 * DHID);
        int rem = idx2 - l * 512 * DHID;
        int r = rem >> 7;
        int kk = rem & 127;
        int sel = r >> 7, rl = r & 127;
        const float* srcm = sel == 0 ? Wq : sel == 1 ? Wk : sel == 2 ? Wv : Ws;
        Wt3[idx2] = f2bf(srcm[l * DHID * DHID + kk * DHID + rl]);
    }
}

// ---------------- input projection: h[M,128](bf16) = x[M,256] @ Wi + bi ----------------
__global__ __launch_bounds__(256) void gemm_in(const float* __restrict__ A, const unsigned short* __restrict__ Wt,
                                               const float* __restrict__ bias, unsigned* __restrict__ h32, int M) {
    __shared__ short As[128 * 128];
    const int tid = threadIdx.x;
    const int lane = tid & 63;
    const int wid = tid >> 6;
    const int row0 = blockIdx.x * 128;
    const int wr = (wid & 1) * 64;
    const int wc = (wid >> 1) * 64;
    f32x4 acc[4][4] = {};
    const int srow = tid >> 1;
    const int sk = (tid & 1) * 64;
    const int grow = min(row0 + srow, M - 1);
    for (int kt = 0; kt < 2; ++kt) {
        const float* ap = A + (size_t)grow * DIN + kt * 128 + sk;
#pragma unroll
        for (int i = 0; i < 8; ++i) {
            float4 f0 = *(const float4*)(ap + i * 8);
            float4 f1 = *(const float4*)(ap + i * 8 + 4);
            short8 s;
            s[0] = f2bf(f0.x); s[1] = f2bf(f0.y); s[2] = f2bf(f0.z); s[3] = f2bf(f0.w);
            s[4] = f2bf(f1.x); s[5] = f2bf(f1.y); s[6] = f2bf(f1.z); s[7] = f2bf(f1.w);
            int g = (sk >> 3) + i;
            *(short8*)(&As[srow * 128 + ((g ^ (srow & 7)) << 3)]) = s;
        }
        __syncthreads();
#pragma unroll
        for (int ks = 0; ks < 4; ++ks) {
            short8 a[4], b[4];
#pragma unroll
            for (int m = 0; m < 4; ++m) {
                int r = wr + m * 16 + (lane & 15);
                int g = ks * 4 + (lane >> 4);
                a[m] = *(const short8*)(&As[r * 128 + ((g ^ (r & 7)) << 3)]);
            }
#pragma unroll
            for (int n = 0; n < 4; ++n) {
                int c = wc + n * 16 + (lane & 15);
                b[n] = *(const short8*)(Wt + (size_t)c * DIN + kt * 128 + ks * 32 + (lane >> 4) * 8);
            }
#pragma unroll
            for (int m = 0; m < 4; ++m)
#pragma unroll
                for (int n = 0; n < 4; ++n)
                    acc[m][n] = __builtin_amdgcn_mfma_f32_16x16x32_bf16(a[m], b[n], acc[m][n], 0, 0, 0);
        }
        __syncthreads();
    }
    // epilogue: per-wave LDS repack (reuse As) -> coalesced uint4 stores
    float* my = ((float*)As) + wid * 1024;
    float bb[4];
#pragma unroll
    for (int n = 0; n < 4; ++n) bb[n] = bias[wc + n * 16 + (lane & 15)];
    const int rr = lane >> 2;
    const int cb = lane & 3;
#pragma unroll
    for (int m = 0; m < 4; ++m) {
#pragma unroll
        for (int n = 0; n < 4; ++n) {
            int lc = n * 16 + (lane & 15);
#pragma unroll
            for (int j = 0; j < 4; ++j) {
                int row = (lane >> 4) * 4 + j;
                my[row * 64 + (((lc >> 2) ^ (row & 7)) << 2) + (lc & 3)] = acc[m][n][j] + bb[n];
            }
        }
        float vals[16];
#pragma unroll
        for (int s = 0; s < 4; ++s) {
            int gx = (cb * 4 + s) ^ (rr & 7);
            f32x4 t4 = *(const f32x4*)(my + rr * 64 + gx * 4);
            vals[s * 4 + 0] = t4.x; vals[s * 4 + 1] = t4.y; vals[s * 4 + 2] = t4.z; vals[s * 4 + 3] = t4.w;
        }
        int grow2 = row0 + wr + m * 16 + rr;
        if (grow2 < M) {
            unsigned pk[8];
#pragma unroll
            for (int d = 0; d < 8; ++d) pk[d] = packbf(vals[2 * d], vals[2 * d + 1]);
            unsigned* op = h32 + (size_t)grow2 * 64 + (wc >> 1) + cb * 8;
            *(uint4*)op = make_uint4(pk[0], pk[1], pk[2], pk[3]);
            *(uint4*)(op + 4) = make_uint4(pk[4], pk[5], pk[6], pk[7]);
        }
    }
}

// ---------------- fused q/k/v/skip GEMM from bf16 h ----------------
__global__ __launch_bounds__(512) void gemm_qkvs(const unsigned short* __restrict__ A,
                                                 const unsigned short* __restrict__ Wt, const float* __restrict__ bq,
                                                 const float* __restrict__ bk, const float* __restrict__ bv,
                                                 const float* __restrict__ bs, unsigned* __restrict__ q32,
                                                 unsigned* __restrict__ kv, unsigned* __restrict__ xr32, int M) {
    __shared__ short As[128 * 128];
    const int tid = threadIdx.x;
    const int lane = tid & 63;
    const int wid = tid >> 6;
    const int row0 = blockIdx.x * 128;
    const int sel = wid >> 2;  // 0: q/skip, 1: k/v
    const int wr = (wid & 1) * 64;
    const int wc = ((wid >> 1) & 1) * 64;
    f32x4 acc0[4][4] = {}, acc1[4][4] = {};
    {
        const int srow = tid >> 2;
        const int sk = (tid & 3) * 32;
        const int grow = min(row0 + srow, M - 1);
        const unsigned short* ap = A + (size_t)grow * DHID + sk;
#pragma unroll
        for (int i = 0; i < 4; ++i) {
            short8 s = *(const short8*)(ap + i * 8);
            int g = (sk >> 3) + i;
            *(short8*)(&As[srow * 128 + ((g ^ (srow & 7)) << 3)]) = s;
        }
    }
    __syncthreads();
    const int b0base = sel ? 128 : 0;    // k : q
    const int b1base = sel ? 256 : 384;  // v : skip
#pragma unroll
    for (int ks = 0; ks < 4; ++ks) {
        short8 a[4], b0[4], b1[4];
#pragma unroll
        for (int m = 0; m < 4; ++m) {
            int r = wr + m * 16 + (lane & 15);
            int g = ks * 4 + (lane >> 4);
            a[m] = *(const short8*)(&As[r * 128 + ((g ^ (r & 7)) << 3)]);
        }
#pragma unroll
        for (int n = 0; n < 4; ++n) {
            int rb = wc + n * 16 + (lane & 15);
            b0[n] = *(const short8*)(Wt + (size_t)(b0base + rb) * DHID + ks * 32 + (lane >> 4) * 8);
            b1[n] = *(const short8*)(Wt + (size_t)(b1base + rb) * DHID + ks * 32 + (lane >> 4) * 8);
        }
#pragma unroll
        for (int m = 0; m < 4; ++m)
#pragma unroll
            for (int n = 0; n < 4; ++n) {
                acc0[m][n] = __builtin_amdgcn_mfma_f32_16x16x32_bf16(a[m], b0[n], acc0[m][n], 0, 0, 0);
                acc1[m][n] = __builtin_amdgcn_mfma_f32_16x16x32_bf16(a[m], b1[n], acc1[m][n], 0, 0, 0);
            }
    }
    __syncthreads();  // done reading As; reuse as repack buffer
    float* my = ((float*)As) + wid * 1024;
    const float* bias0 = sel ? bk : bq;
    const float* bias1 = sel ? bv : bs;
    float bb0[4], bb1[4];
#pragma unroll
    for (int n = 0; n < 4; ++n) {
        int c = wc + n * 16 + (lane & 15);
        bb0[n] = bias0[c];
        bb1[n] = bias1[c];
    }
    const int rr = lane >> 2;
    const int cb = lane & 3;
#pragma unroll
    for (int m = 0; m < 4; ++m) {
        float vals0[16], vals1[16];
#pragma unroll
        for (int n = 0; n < 4; ++n) {
            int lc = n * 16 + (lane & 15);
#pragma unroll
            for (int j = 0; j < 4; ++j) {
                int row = (lane >> 4) * 4 + j;
                my[row * 64 + (((lc >> 2) ^ (row & 7)) << 2) + (lc & 3)] = acc0[m][n][j] + bb0[n];
            }
        }
#pragma unroll
        for (int s = 0; s < 4; ++s) {
            int gx = (cb * 4 + s) ^ (rr & 7);
            f32x4 t4 = *(const f32x4*)(my + rr * 64 + gx * 4);
            vals0[s * 4 + 0] = t4.x; vals0[s * 4 + 1] = t4.y; vals0[s * 4 + 2] = t4.z; vals0[s * 4 + 3] = t4.w;
        }
#pragma unroll
        for (int n = 0; n < 4; ++n) {
            int lc = n * 16 + (lane & 15);
#pragma unroll
            for (int j = 0; j < 4; ++j) {
                int row = (lane >> 4) * 4 + j;
                my[row * 64 + (((lc >> 2) ^ (row & 7)) << 2) + (lc & 3)] = acc1[m][n][j] + bb1[n];
            }
        }
#pragma unroll
        for (int s = 0; s < 4; ++s) {
            int gx = (cb * 4 + s) ^ (rr & 7);
            f32x4 t4 = *(const f32x4*)(my + rr * 64 + gx * 4);
            vals1[s * 4 + 0] = t4.x; vals1[s * 4 + 1] = t4.y; vals1[s * 4 + 2] = t4.z; vals1[s * 4 + 3] = t4.w;
        }
        int grow2 = row0 + wr + m * 16 + rr;
        if (grow2 < M) {
            size_t obase = (size_t)grow2 * 64 + (wc >> 1) + cb * 8;
            if (sel == 0) {
                unsigned p0[8], p1[8];
#pragma unroll
                for (int d = 0; d < 8; ++d) {
                    p0[d] = packbf(vals0[2 * d], vals0[2 * d + 1]);
                    p1[d] = packbf(vals1[2 * d], vals1[2 * d + 1]);
                }
                *(uint4*)(q32 + obase) = make_uint4(p0[0], p0[1], p0[2], p0[3]);
                *(uint4*)(q32 + obase + 4) = make_uint4(p0[4], p0[5], p0[6], p0[7]);
                *(uint4*)(xr32 + obase) = make_uint4(p1[0], p1[1], p1[2], p1[3]);
                *(uint4*)(xr32 + obase + 4) = make_uint4(p1[4], p1[5], p1[6], p1[7]);
            } else {
                unsigned pk[8];
#pragma unroll
                for (int d = 0; d < 8; ++d) {
                    unsigned u = (unsigned)__builtin_amdgcn_cvt_pk_fp8_f32(vals0[2 * d], vals0[2 * d + 1], 0, false);
                    u = (unsigned)__builtin_amdgcn_cvt_pk_fp8_f32(vals1[2 * d], vals1[2 * d + 1], (int)u, true);
                    pk[d] = u;
                }
                *(uint4*)(kv + obase) = make_uint4(pk[0], pk[1], pk[2], pk[3]);
                *(uint4*)(kv + obase + 4) = make_uint4(pk[4], pk[5], pk[6], pk[7]);
            }
        }
    }
}

// ---------------- per-node attention + beta-gate + GELU + LayerNorm ----------------
// One wave per node; 8 edge-subgroups (g=lane>>3), lane owns 16 consecutive channels (8 kv dwords, 2 uint4).
// Head = (lane&7)>>1; head dot-reduce = single DPP quad_perm xor1. Meta staged in LDS (broadcast ds_read_b64);
// depth-1 prefetch of next iteration's meta+kv rows. exp2-domain online softmax with defer-max.
// houtb may alias res32 (same-wave RAW only).
__global__ __launch_bounds__(256) void node_attn_fuse(const unsigned* __restrict__ q32,
                                                      const unsigned* __restrict__ kv, const int2* __restrict__ esrc,
                                                      const float* __restrict__ We, const int* __restrict__ row_ptr,
                                                      const unsigned* __restrict__ xr32, const unsigned* res32,
                                                      const float* __restrict__ Wb, const float* __restrict__ lng,
                                                      const float* __restrict__ lnb, unsigned* houtb, float* houtf) {
    __shared__ float sh_o[4][128];
    __shared__ int2 sh_meta[4][64];
    const int tid = threadIdx.x;
    const int wv = tid >> 6;
    const int lane = tid & 63;
    const int wid = blockIdx.x * 4 + wv;
    if (wid >= NNODES) return;
    const int ln = lane & 7;  // channel group: channels 16*ln .. 16*ln+15 (dwords 8*ln..8*ln+7)
    const int g = lane >> 3;  // edge subgroup 0..7
    const int base = row_ptr[wid], end = row_ptr[wid + 1];
    const float SC = 0.25505654047688565f;  // (1/sqrt(32)) * log2(e)
    const float THR = 8.0f;

    float qv[16];
    {
        uint4 qa = *(const uint4*)(q32 + (size_t)wid * 64 + 8 * ln);
        uint4 qb = *(const uint4*)(q32 + (size_t)wid * 64 + 8 * ln + 4);
        unsigned qd[8] = {qa.x, qa.y, qa.z, qa.w, qb.x, qb.y, qb.z, qb.w};
#pragma unroll
        for (int t = 0; t < 8; ++t) {
            qv[2 * t] = bf2f((unsigned short)qd[t]) * SC;
            qv[2 * t + 1] = bf2f((unsigned short)(qd[t] >> 16)) * SC;
        }
    }
    float qwe;
    {
        float s = 0.f;
#pragma unroll
        for (int t = 0; t < 4; ++t) {
            float4 w4 = *(const float4*)(We + 16 * ln + 4 * t);
            s = fmaf(qv[4 * t], w4.x, s);
            s = fmaf(qv[4 * t + 1], w4.y, s);
            s = fmaf(qv[4 * t + 2], w4.z, s);
            s = fmaf(qv[4 * t + 3], w4.w, s);
        }
        qwe = s + dpp_xor1(s);  // per-head q·we (scaled)
    }

    float m = -1e30f, sden = 0.f, tacc = 0.f;
    float acc[16] = {};
    const unsigned* kvp = kv + 8 * ln;

    for (int cbse = base; cbse < end; cbse += 64) {
        int cnt = min(end - cbse, 64);
        int2 me = (lane < cnt) ? esrc[cbse + lane] : make_int2(0, 0);
        sh_meta[wv][lane] = me;
        __asm__ volatile("s_waitcnt lgkmcnt(0)" ::: "memory");  // same-wave LDS RAW
        int jmax = (cnt + 7) >> 3;
        int2 mc = sh_meta[wv][g];
        const unsigned* rowp = kvp + (size_t)mc.x * 64;
        uint4 ka = *(const uint4*)rowp;
        uint4 kb = *(const uint4*)(rowp + 4);
        for (int j = 0; j < jmax; ++j) {
            // depth-1 prefetch of next iteration
            bool more = (j + 1 < jmax);
            int2 mn_ = sh_meta[wv][(((j + 1) << 3) + g) & 63];
            uint4 ka1 = ka, kb1 = kb;
            if (more) {
                const unsigned* rowp1 = kvp + (size_t)mn_.x * 64;
                ka1 = *(const uint4*)rowp1;
                kb1 = *(const uint4*)(rowp1 + 4);
            }
            bool valid = ((j << 3) + g) < cnt;
            float av = __int_as_float(mc.y);
            unsigned kd[8] = {ka.x, ka.y, ka.z, ka.w, kb.x, kb.y, kb.z, kb.w};
            float vj[16];
            float p = 0.f;
#pragma unroll
            for (int t = 0; t < 8; ++t) {
                f32x2 kk = __builtin_amdgcn_cvt_pk_f32_fp8((int)kd[t], false);
                f32x2 vvv = __builtin_amdgcn_cvt_pk_f32_fp8((int)kd[t], true);
                p = fmaf(qv[2 * t], kk.x, p);
                p = fmaf(qv[2 * t + 1], kk.y, p);
                vj[2 * t] = vvv.x;
                vj[2 * t + 1] = vvv.y;
            }
            p += dpp_xor1(p);  // head dot over 32 ch (2 lanes)
            p = fmaf(av, qwe, p);
            p = valid ? p : -3e38f;
            if (__all(p - m <= THR)) {
                float wgt = exp2f(p - m);
                sden += wgt;
                tacc = fmaf(wgt, av, tacc);
#pragma unroll
                for (int i = 0; i < 16; ++i) acc[i] = fmaf(wgt, vj[i], acc[i]);
            } else {
                float mn2 = fmaxf(m, p);
                float wgt = exp2f(p - mn2);
                float sc = exp2f(m - mn2);
                sden = fmaf(sden, sc, wgt);
                tacc = fmaf(tacc, sc, wgt * av);
#pragma unroll
                for (int i = 0; i < 16; ++i) acc[i] = fmaf(acc[i], sc, wgt * vj[i]);
                m = mn2;
            }
            mc = mn_;
            ka = ka1;
            kb = kb1;
        }
    }

    // merge the 8 subgroup partial states: xor8 via DPP, then xor16/xor32 via shfl
    {
        float m_o = dpp_xor8(m), s_o = dpp_xor8(sden), t_o = dpp_xor8(tacc);
        float mn2 = fmaxf(m, m_o);
        float sa = exp2f(m - mn2), sb = exp2f(m_o - mn2);
        sden = sden * sa + s_o * sb;
        tacc = tacc * sa + t_o * sb;
#pragma unroll
        for (int i = 0; i < 16; ++i) acc[i] = acc[i] * sa + dpp_xor8(acc[i]) * sb;
        m = mn2;
    }
#pragma unroll
    for (int off = 16; off <= 32; off <<= 1) {
        float m_o = __shfl_xor(m, off);
        float s_o = __shfl_xor(sden, off);
        float t_o = __shfl_xor(tacc, off);
        float mn2 = fmaxf(m, m_o);
        float sa = exp2f(m - mn2), sb = exp2f(m_o - mn2);
        sden = sden * sa + s_o * sb;
        tacc = tacc * sa + t_o * sb;
#pragma unroll
        for (int i = 0; i < 16; ++i) acc[i] = acc[i] * sa + __shfl_xor(acc[i], off) * sb;
        m = mn2;
    }
    float rden = 1.f / (sden + 1e-16f);
    if (g == 0) {
#pragma unroll
        for (int t = 0; t < 4; ++t) {
            float4 w4 = *(const float4*)(We + 16 * ln + 4 * t);
            float4 o4;
            o4.x = fmaf(tacc, w4.x, acc[4 * t]) * rden;
            o4.y = fmaf(tacc, w4.y, acc[4 * t + 1]) * rden;
            o4.z = fmaf(tacc, w4.z, acc[4 * t + 2]) * rden;
            o4.w = fmaf(tacc, w4.w, acc[4 * t + 3]) * rden;
            *(float4*)(&sh_o[wv][16 * ln + 4 * t]) = o4;
        }
    }
    __asm__ volatile("s_waitcnt lgkmcnt(0)" ::: "memory");  // same-wave LDS RAW

    // ---- epilogue: lane owns channels (2*lane, 2*lane+1) ----
    const int c0 = 2 * lane;
    const float2 ov0v = *(const float2*)(&sh_o[wv][c0]);
    float o0 = ov0v.x, o1 = ov0v.y;
    const unsigned xw = xr32[(size_t)wid * 64 + lane];
    const float x0 = bf2f((unsigned short)xw), x1 = bf2f((unsigned short)(xw >> 16));
    const float2 w0 = *(const float2*)(Wb + c0);
    const float2 w1 = *(const float2*)(Wb + 128 + c0);
    const float2 w2 = *(const float2*)(Wb + 256 + c0);
    float bl = o0 * w0.x + o1 * w0.y + x0 * w1.x + x1 * w1.y + (o0 - x0) * w2.x + (o1 - x1) * w2.y;
#pragma unroll
    for (int off = 32; off; off >>= 1) bl += __shfl_xor(bl, off);
    float beta = 1.f / (1.f + __expf(-bl));
    float g0 = beta * x0 + (1.f - beta) * o0;
    float g1 = beta * x1 + (1.f - beta) * o1;
    g0 = 0.5f * g0 * (1.f + erff(g0 * 0.70710678118654752f));
    g1 = 0.5f * g1 * (1.f + erff(g1 * 0.70710678118654752f));
    const unsigned rw = res32[(size_t)wid * 64 + lane];
    float t0 = g0 + bf2f((unsigned short)rw);
    float t1 = g1 + bf2f((unsigned short)(rw >> 16));
    float su = t0 + t1, sq = t0 * t0 + t1 * t1;
#pragma unroll
    for (int off = 32; off; off >>= 1) {
        su += __shfl_xor(su, off);
        sq += __shfl_xor(sq, off);
    }
    float mu = su * (1.f / 128.f);
    float var = sq * (1.f / 128.f) - mu * mu;
    float inv = rsqrtf(var + 1e-5f);
    const float2 gv = *(const float2*)(lng + c0);
    const float2 bv2 = *(const float2*)(lnb + c0);
    float ovx = (t0 - mu) * inv * gv.x + bv2.x;
    float ovy = (t1 - mu) * inv * gv.y + bv2.y;
    if (houtf) {
        *(float2*)(houtf + (size_t)wid * 128 + c0) = make_float2(ovx, ovy);
    } else {
        houtb[(size_t)wid * 64 + lane] = packbf(ovx, ovy);
    }
}

extern "C" void kernel_launch(void* const* d_in, const int* in_sizes, int n_in, void* d_out, int out_size,
                              void* d_ws, size_t ws_size, hipStream_t stream) {
    const float* x = (const float*)d_in[0];
    const int* ei = (const int*)d_in[1];
    const float* ea = (const float*)d_in[2];
    const float* Wi = (const float*)d_in[3];
    const float* bi = (const float*)d_in[4];
    const float* Wq = (const float*)d_in[5];
    const float* bq = (const float*)d_in[6];
    const float* Wk = (const float*)d_in[7];
    const float* bk = (const float*)d_in[8];
    const float* Wv = (const float*)d_in[9];
    const float* bv = (const float*)d_in[10];
    const float* We = (const float*)d_in[11];
    const float* Wskip = (const float*)d_in[12];
    const float* bskip = (const float*)d_in[13];
    const float* Wbeta = (const float*)d_in[14];
    const float* lng = (const float*)d_in[15];
    const float* lnb = (const float*)d_in[16];

    const int* srcp = ei;
    const int* dstp = ei + NEDGES;

    char* p = (char*)d_ws;
    auto alloc = [&](size_t bytes) {
        void* r = (void*)p;
        p += (bytes + 255) & ~(size_t)255;
        return r;
    };
    unsigned* h32 = (unsigned*)alloc((size_t)NNODES * 64 * 4);
    unsigned* q32 = (unsigned*)alloc((size_t)NNODES * 64 * 4);
    unsigned* xr32 = (unsigned*)alloc((size_t)NNODES * 64 * 4);
    unsigned* kv = (unsigned*)alloc((size_t)NNODES * 64 * 4);
    unsigned short* Wit = (unsigned short*)alloc((size_t)DHID * DIN * 2);
    unsigned short* Wt3 = (unsigned short*)alloc((size_t)3 * 512 * DHID * 2);
    int* counts = (int*)alloc((size_t)NNODES * 4);
    int* row_ptr = (int*)alloc((size_t)(NNODES + 1) * 4);
    int2* esrc = (int2*)alloc((size_t)NEDGES * 8);
    int* partials = (int*)alloc(256 * 4);

    const int EB = (NEDGES + 255) / 256;
    const int NB = (NNODES + 255) / 256;
    const int GB = (NNODES + 127) / 128;  // 391
    const int WB = (NNODES + 3) / 4;      // 12500 (4 waves/block, 1 node/wave)
    const int PB = (DHID * DIN + 3 * 512 * DHID + 255) / 256;

    prep_w<<<PB, 256, 0, stream>>>(Wi, Wq, Wk, Wv, Wskip, Wit, Wt3);

    // CSR by dst (single memset; scatter consumes the degree histogram via atomicSub)
    hipMemsetAsync(counts, 0, (size_t)NNODES * 4, stream);
    k_hist<<<EB, 256, 0, stream>>>(dstp, counts);
    k_scan_block<<<NB, 256, 0, stream>>>(counts, row_ptr + 1, partials, NNODES);
    k_apply2<<<NB, 256, 0, stream>>>(partials, row_ptr, NNODES, NB);
    k_scatter<<<EB, 256, 0, stream>>>(srcp, dstp, ea, row_ptr, counts, esrc);

    gemm_in<<<GB, 256, 0, stream>>>(x, Wit, bi, h32, NNODES);

    for (int l = 0; l < 3; ++l) {
        const size_t bo = (size_t)l * 128;
        gemm_qkvs<<<GB, 512, 0, stream>>>((const unsigned short*)h32, Wt3 + (size_t)l * 512 * DHID, bq + bo, bk + bo,
                                          bv + bo, bskip + bo, q32, kv, xr32, NNODES);
        node_attn_fuse<<<WB, 256, 0, stream>>>(q32, kv, esrc, We + bo, row_ptr, xr32, h32,
                                               Wbeta + (size_t)l * 384, lng + bo, lnb + bo, h32,
                                               (l == 2) ? (float*)d_out : nullptr);
    }
}

// Round 10
// 330.407 us; speedup vs baseline: 1.2782x; 1.2782x over previous
//
#include <hip/hip_runtime.h>
#include <math.h>

#define NNODES 50000
#define NEDGES 800000
#define DIN 256
#define DHID 128

typedef __attribute__((ext_vector_type(8))) short short8;
typedef __attribute__((ext_vector_type(4))) float f32x4;
typedef __attribute__((ext_vector_type(2))) float f32x2;

__device__ __forceinline__ unsigned short f2bf(float f) {
    unsigned u = __builtin_bit_cast(unsigned, f);
    u += 0x7fffu + ((u >> 16) & 1u);  // RNE
    return (unsigned short)(u >> 16);
}
__device__ __forceinline__ float bf2f(unsigned short s) {
    return __builtin_bit_cast(float, (unsigned)s << 16);
}
__device__ __forceinline__ unsigned packbf(float a, float b) {
    return (unsigned)f2bf(a) | ((unsigned)f2bf(b) << 16);
}
// DPP helpers: full-rate VALU cross-lane (no LDS)
__device__ __forceinline__ float dpp_xor1(float x) {  // quad_perm [1,0,3,2]
    return __builtin_bit_cast(float, __builtin_amdgcn_update_dpp(0, __builtin_bit_cast(int, x), 0xB1, 0xF, 0xF, true));
}
__device__ __forceinline__ float dpp_xor2(float x) {  // quad_perm [2,3,0,1]
    return __builtin_bit_cast(float, __builtin_amdgcn_update_dpp(0, __builtin_bit_cast(int, x), 0x4E, 0xF, 0xF, true));
}
__device__ __forceinline__ float dpp_hmirror(float x) {  // row_half_mirror (i ^ reverse within 8)
    return __builtin_bit_cast(float, __builtin_amdgcn_update_dpp(0, __builtin_bit_cast(int, x), 0x141, 0xF, 0xF, true));
}
__device__ __forceinline__ float dpp_mirror(float x) {  // row_mirror (reverse within 16)
    return __builtin_bit_cast(float, __builtin_amdgcn_update_dpp(0, __builtin_bit_cast(int, x), 0x140, 0xF, 0xF, true));
}
// sum over the 16-lane row
__device__ __forceinline__ float red16(float x) {
    x += dpp_xor1(x);
    x += dpp_xor2(x);
    x += dpp_hmirror(x);
    x += dpp_mirror(x);
    return x;
}

// ---------------- CSR build ----------------
__global__ __launch_bounds__(256) void k_hist(const int* __restrict__ dst, int* __restrict__ counts) {
    int e = blockIdx.x * 256 + threadIdx.x;
    if (e < NEDGES) atomicAdd(&counts[dst[e]], 1);
}

__global__ __launch_bounds__(256) void k_scan_block(const int* __restrict__ in, int* __restrict__ out,
                                                    int* __restrict__ partials, int n) {
    __shared__ int sh[256];
    int tid = threadIdx.x;
    int i = blockIdx.x * 256 + tid;
    int vv = (i < n) ? in[i] : 0;
    sh[tid] = vv;
    __syncthreads();
    for (int off = 1; off < 256; off <<= 1) {
        int t = (tid >= off) ? sh[tid - off] : 0;
        __syncthreads();
        sh[tid] += t;
        __syncthreads();
    }
    if (i < n) out[i] = sh[tid];
    if (tid == 255) partials[blockIdx.x] = sh[255];
}

// merged: every block locally scans the (<=256) partials, then applies its prefix
__global__ __launch_bounds__(256) void k_apply2(const int* __restrict__ partials, int* __restrict__ row_ptr, int n,
                                                int nb) {
    __shared__ int sh[256];
    int tid = threadIdx.x;
    int vv = (tid < nb) ? partials[tid] : 0;
    sh[tid] = vv;
    __syncthreads();
    for (int off = 1; off < 256; off <<= 1) {
        int t = (tid >= off) ? sh[tid - off] : 0;
        __syncthreads();
        sh[tid] += t;
        __syncthreads();
    }
    int i = blockIdx.x * 256 + tid;
    if (i < n) {
        int add = blockIdx.x ? sh[blockIdx.x - 1] : 0;
        row_ptr[i + 1] += add;
    }
    if (i == 0) row_ptr[0] = 0;
}

// dst-sorted (src, ea) pairs; fill holds degrees (from hist), consumed by atomicSub
__global__ __launch_bounds__(256) void k_scatter(const int* __restrict__ src, const int* __restrict__ dst,
                                                 const float* __restrict__ ea, const int* __restrict__ row_ptr,
                                                 int* __restrict__ fill, int2* __restrict__ esrc) {
    int e = blockIdx.x * 256 + threadIdx.x;
    if (e < NEDGES) {
        int d = dst[e];
        int old = atomicSub(&fill[d], 1);
        int pos = row_ptr[d] + old - 1;
        esrc[pos] = make_int2(src[e], __float_as_int(ea[e]));
    }
}

// ---------------- weight prep: transpose + bf16 cast (merged) ----------------
__global__ __launch_bounds__(256) void prep_w(const float* __restrict__ Wi, const float* __restrict__ Wq,
                                              const float* __restrict__ Wk, const float* __restrict__ Wv,
                                              const float* __restrict__ Ws, unsigned short* __restrict__ Wit,
                                              unsigned short* __restrict__ Wt3) {
    int idx = blockIdx.x * 256 + threadIdx.x;
    if (idx < DHID * DIN) {
        int n = idx >> 8, kk = idx & 255;
        Wit[idx] = f2bf(Wi[kk * DHID + n]);
    }
    int idx2 = idx - DHID * DIN;
    if (idx2 >= 0 && idx2 < 3 * 512 * DHID) {
        int l = idx2 / (512 * DHID);
        int rem = idx2 - l * 512 * DHID;
        int r = rem >> 7;
        int kk = rem & 127;
        int sel = r >> 7, rl = r & 127;
        const float* srcm = sel == 0 ? Wq : sel == 1 ? Wk : sel == 2 ? Wv : Ws;
        Wt3[idx2] = f2bf(srcm[l * DHID * DHID + kk * DHID + rl]);
    }
}

// ---------------- input projection: h[M,128](bf16) = x[M,256] @ Wi + bi ----------------
__global__ __launch_bounds__(256) void gemm_in(const float* __restrict__ A, const unsigned short* __restrict__ Wt,
                                               const float* __restrict__ bias, unsigned* __restrict__ h32, int M) {
    __shared__ short As[128 * 128];
    const int tid = threadIdx.x;
    const int lane = tid & 63;
    const int wid = tid >> 6;
    const int row0 = blockIdx.x * 128;
    const int wr = (wid & 1) * 64;
    const int wc = (wid >> 1) * 64;
    f32x4 acc[4][4] = {};
    const int srow = tid >> 1;
    const int sk = (tid & 1) * 64;
    const int grow = min(row0 + srow, M - 1);
    for (int kt = 0; kt < 2; ++kt) {
        const float* ap = A + (size_t)grow * DIN + kt * 128 + sk;
#pragma unroll
        for (int i = 0; i < 8; ++i) {
            float4 f0 = *(const float4*)(ap + i * 8);
            float4 f1 = *(const float4*)(ap + i * 8 + 4);
            short8 s;
            s[0] = f2bf(f0.x); s[1] = f2bf(f0.y); s[2] = f2bf(f0.z); s[3] = f2bf(f0.w);
            s[4] = f2bf(f1.x); s[5] = f2bf(f1.y); s[6] = f2bf(f1.z); s[7] = f2bf(f1.w);
            int g = (sk >> 3) + i;
            *(short8*)(&As[srow * 128 + ((g ^ (srow & 7)) << 3)]) = s;
        }
        __syncthreads();
#pragma unroll
        for (int ks = 0; ks < 4; ++ks) {
            short8 a[4], b[4];
#pragma unroll
            for (int m = 0; m < 4; ++m) {
                int r = wr + m * 16 + (lane & 15);
                int g = ks * 4 + (lane >> 4);
                a[m] = *(const short8*)(&As[r * 128 + ((g ^ (r & 7)) << 3)]);
            }
#pragma unroll
            for (int n = 0; n < 4; ++n) {
                int c = wc + n * 16 + (lane & 15);
                b[n] = *(const short8*)(Wt + (size_t)c * DIN + kt * 128 + ks * 32 + (lane >> 4) * 8);
            }
#pragma unroll
            for (int m = 0; m < 4; ++m)
#pragma unroll
                for (int n = 0; n < 4; ++n)
                    acc[m][n] = __builtin_amdgcn_mfma_f32_16x16x32_bf16(a[m], b[n], acc[m][n], 0, 0, 0);
        }
        __syncthreads();
    }
    // epilogue: per-wave LDS repack (reuse As) -> coalesced uint4 stores
    float* my = ((float*)As) + wid * 1024;
    float bb[4];
#pragma unroll
    for (int n = 0; n < 4; ++n) bb[n] = bias[wc + n * 16 + (lane & 15)];
    const int rr = lane >> 2;
    const int cb = lane & 3;
#pragma unroll
    for (int m = 0; m < 4; ++m) {
#pragma unroll
        for (int n = 0; n < 4; ++n) {
            int lc = n * 16 + (lane & 15);
#pragma unroll
            for (int j = 0; j < 4; ++j) {
                int row = (lane >> 4) * 4 + j;
                my[row * 64 + (((lc >> 2) ^ (row & 7)) << 2) + (lc & 3)] = acc[m][n][j] + bb[n];
            }
        }
        float vals[16];
#pragma unroll
        for (int s = 0; s < 4; ++s) {
            int gx = (cb * 4 + s) ^ (rr & 7);
            f32x4 t4 = *(const f32x4*)(my + rr * 64 + gx * 4);
            vals[s * 4 + 0] = t4.x; vals[s * 4 + 1] = t4.y; vals[s * 4 + 2] = t4.z; vals[s * 4 + 3] = t4.w;
        }
        int grow2 = row0 + wr + m * 16 + rr;
        if (grow2 < M) {
            unsigned pk[8];
#pragma unroll
            for (int d = 0; d < 8; ++d) pk[d] = packbf(vals[2 * d], vals[2 * d + 1]);
            unsigned* op = h32 + (size_t)grow2 * 64 + (wc >> 1) + cb * 8;
            *(uint4*)op = make_uint4(pk[0], pk[1], pk[2], pk[3]);
            *(uint4*)(op + 4) = make_uint4(pk[4], pk[5], pk[6], pk[7]);
        }
    }
}

// ---------------- fused q/k/v/skip GEMM from bf16 h ----------------
__global__ __launch_bounds__(512) void gemm_qkvs(const unsigned short* __restrict__ A,
                                                 const unsigned short* __restrict__ Wt, const float* __restrict__ bq,
                                                 const float* __restrict__ bk, const float* __restrict__ bv,
                                                 const float* __restrict__ bs, unsigned* __restrict__ q32,
                                                 unsigned* __restrict__ kv, unsigned* __restrict__ xr32, int M) {
    __shared__ short As[128 * 128];
    const int tid = threadIdx.x;
    const int lane = tid & 63;
    const int wid = tid >> 6;
    const int row0 = blockIdx.x * 128;
    const int sel = wid >> 2;  // 0: q/skip, 1: k/v
    const int wr = (wid & 1) * 64;
    const int wc = ((wid >> 1) & 1) * 64;
    f32x4 acc0[4][4] = {}, acc1[4][4] = {};
    {
        const int srow = tid >> 2;
        const int sk = (tid & 3) * 32;
        const int grow = min(row0 + srow, M - 1);
        const unsigned short* ap = A + (size_t)grow * DHID + sk;
#pragma unroll
        for (int i = 0; i < 4; ++i) {
            short8 s = *(const short8*)(ap + i * 8);
            int g = (sk >> 3) + i;
            *(short8*)(&As[srow * 128 + ((g ^ (srow & 7)) << 3)]) = s;
        }
    }
    __syncthreads();
    const int b0base = sel ? 128 : 0;    // k : q
    const int b1base = sel ? 256 : 384;  // v : skip
#pragma unroll
    for (int ks = 0; ks < 4; ++ks) {
        short8 a[4], b0[4], b1[4];
#pragma unroll
        for (int m = 0; m < 4; ++m) {
            int r = wr + m * 16 + (lane & 15);
            int g = ks * 4 + (lane >> 4);
            a[m] = *(const short8*)(&As[r * 128 + ((g ^ (r & 7)) << 3)]);
        }
#pragma unroll
        for (int n = 0; n < 4; ++n) {
            int rb = wc + n * 16 + (lane & 15);
            b0[n] = *(const short8*)(Wt + (size_t)(b0base + rb) * DHID + ks * 32 + (lane >> 4) * 8);
            b1[n] = *(const short8*)(Wt + (size_t)(b1base + rb) * DHID + ks * 32 + (lane >> 4) * 8);
        }
#pragma unroll
        for (int m = 0; m < 4; ++m)
#pragma unroll
            for (int n = 0; n < 4; ++n) {
                acc0[m][n] = __builtin_amdgcn_mfma_f32_16x16x32_bf16(a[m], b0[n], acc0[m][n], 0, 0, 0);
                acc1[m][n] = __builtin_amdgcn_mfma_f32_16x16x32_bf16(a[m], b1[n], acc1[m][n], 0, 0, 0);
            }
    }
    __syncthreads();  // done reading As; reuse as repack buffer
    float* my = ((float*)As) + wid * 1024;
    const float* bias0 = sel ? bk : bq;
    const float* bias1 = sel ? bv : bs;
    float bb0[4], bb1[4];
#pragma unroll
    for (int n = 0; n < 4; ++n) {
        int c = wc + n * 16 + (lane & 15);
        bb0[n] = bias0[c];
        bb1[n] = bias1[c];
    }
    const int rr = lane >> 2;
    const int cb = lane & 3;
#pragma unroll
    for (int m = 0; m < 4; ++m) {
        float vals0[16], vals1[16];
#pragma unroll
        for (int n = 0; n < 4; ++n) {
            int lc = n * 16 + (lane & 15);
#pragma unroll
            for (int j = 0; j < 4; ++j) {
                int row = (lane >> 4) * 4 + j;
                my[row * 64 + (((lc >> 2) ^ (row & 7)) << 2) + (lc & 3)] = acc0[m][n][j] + bb0[n];
            }
        }
#pragma unroll
        for (int s = 0; s < 4; ++s) {
            int gx = (cb * 4 + s) ^ (rr & 7);
            f32x4 t4 = *(const f32x4*)(my + rr * 64 + gx * 4);
            vals0[s * 4 + 0] = t4.x; vals0[s * 4 + 1] = t4.y; vals0[s * 4 + 2] = t4.z; vals0[s * 4 + 3] = t4.w;
        }
#pragma unroll
        for (int n = 0; n < 4; ++n) {
            int lc = n * 16 + (lane & 15);
#pragma unroll
            for (int j = 0; j < 4; ++j) {
                int row = (lane >> 4) * 4 + j;
                my[row * 64 + (((lc >> 2) ^ (row & 7)) << 2) + (lc & 3)] = acc1[m][n][j] + bb1[n];
            }
        }
#pragma unroll
        for (int s = 0; s < 4; ++s) {
            int gx = (cb * 4 + s) ^ (rr & 7);
            f32x4 t4 = *(const f32x4*)(my + rr * 64 + gx * 4);
            vals1[s * 4 + 0] = t4.x; vals1[s * 4 + 1] = t4.y; vals1[s * 4 + 2] = t4.z; vals1[s * 4 + 3] = t4.w;
        }
        int grow2 = row0 + wr + m * 16 + rr;
        if (grow2 < M) {
            size_t obase = (size_t)grow2 * 64 + (wc >> 1) + cb * 8;
            if (sel == 0) {
                unsigned p0[8], p1[8];
#pragma unroll
                for (int d = 0; d < 8; ++d) {
                    p0[d] = packbf(vals0[2 * d], vals0[2 * d + 1]);
                    p1[d] = packbf(vals1[2 * d], vals1[2 * d + 1]);
                }
                *(uint4*)(q32 + obase) = make_uint4(p0[0], p0[1], p0[2], p0[3]);
                *(uint4*)(q32 + obase + 4) = make_uint4(p0[4], p0[5], p0[6], p0[7]);
                *(uint4*)(xr32 + obase) = make_uint4(p1[0], p1[1], p1[2], p1[3]);
                *(uint4*)(xr32 + obase + 4) = make_uint4(p1[4], p1[5], p1[6], p1[7]);
            } else {
                unsigned pk[8];
#pragma unroll
                for (int d = 0; d < 8; ++d) {
                    unsigned u = (unsigned)__builtin_amdgcn_cvt_pk_fp8_f32(vals0[2 * d], vals0[2 * d + 1], 0, false);
                    u = (unsigned)__builtin_amdgcn_cvt_pk_fp8_f32(vals1[2 * d], vals1[2 * d + 1], (int)u, true);
                    pk[d] = u;
                }
                *(uint4*)(kv + obase) = make_uint4(pk[0], pk[1], pk[2], pk[3]);
                *(uint4*)(kv + obase + 4) = make_uint4(pk[4], pk[5], pk[6], pk[7]);
            }
        }
    }
}

// ---------------- per-node attention + beta-gate + GELU + LayerNorm ----------------
// 4 nodes per wave: 16-lane group per node, lane owns 8 consecutive channels (4 kv dwords = 1 uint4).
// Head = (lane&15)>>2; head dot-reduce = 2 DPP quad-perm adds; NO cross-subgroup merge needed.
// Meta via __shfl (bpermute), depth-1 register prefetch of next edge's kv row. Zero LDS.
// Algebra: logit = q·k + av*(q·we);  out = (Σw·v + (Σw·av)·we)/Σw. exp2-domain, defer-max.
// houtb may alias res32 (same-wave RAW only).
__global__ __launch_bounds__(256) void node_attn_fuse(const unsigned* __restrict__ q32,
                                                      const unsigned* __restrict__ kv, const int2* __restrict__ esrc,
                                                      const float* __restrict__ We, const int* __restrict__ row_ptr,
                                                      const unsigned* __restrict__ xr32, const unsigned* res32,
                                                      const float* __restrict__ Wb, const float* __restrict__ lng,
                                                      const float* __restrict__ lnb, unsigned* houtb, float* houtf) {
    const int tid = threadIdx.x;
    const int lane = tid & 63;
    const int lnl = lane & 15;   // lane within node group
    const int gbase = lane & 48; // group base lane
    const int node = blockIdx.x * 16 + (tid >> 4);  // 16 nodes per block (4 waves x 4 groups); 50000 = 3125*16 exact
    const int base = row_ptr[node], end = row_ptr[node + 1];
    const float SC = 0.25505654047688565f;  // (1/sqrt(32)) * log2(e)
    const float THR = 8.0f;

    // q (8 ch, scaled) and We slice
    float qv[8], wev[8];
    {
        uint4 qw = *(const uint4*)(q32 + (size_t)node * 64 + 4 * lnl);
        unsigned qd[4] = {qw.x, qw.y, qw.z, qw.w};
#pragma unroll
        for (int t = 0; t < 4; ++t) {
            qv[2 * t] = bf2f((unsigned short)qd[t]) * SC;
            qv[2 * t + 1] = bf2f((unsigned short)(qd[t] >> 16)) * SC;
        }
        float4 wlo = *(const float4*)(We + 8 * lnl);
        float4 whi = *(const float4*)(We + 8 * lnl + 4);
        wev[0] = wlo.x; wev[1] = wlo.y; wev[2] = wlo.z; wev[3] = wlo.w;
        wev[4] = whi.x; wev[5] = whi.y; wev[6] = whi.z; wev[7] = whi.w;
    }
    float qwe;
    {
        float s = 0.f;
#pragma unroll
        for (int i = 0; i < 8; ++i) s = fmaf(qv[i], wev[i], s);
        s += dpp_xor1(s);
        s += dpp_xor2(s);  // per-head (4-lane quad) q·we
        qwe = s;
    }

    float m = -1e30f, sden = 0.f, tacc = 0.f;
    float acc[8] = {};
    const unsigned* kvp = kv + 4 * lnl;

    for (int off = 0; ; off += 16) {
        int cnt = min(end - base - off, 16);  // per-group; may be <= 0
        if (__all(cnt <= 0)) break;
        int s_l = 0;
        float a_l = 0.f;
        if (lnl < cnt) {
            int2 sa = esrc[base + off + lnl];
            s_l = sa.x;
            a_l = __int_as_float(sa.y);
        }
        // wave-uniform iteration limit = max cnt over the 4 groups
        int cm = max(cnt, 0);
        cm = max(cm, __shfl_xor(cm, 16));
        cm = max(cm, __shfl_xor(cm, 32));
        // prefetch j=0
        int src_n = __shfl(s_l, gbase);
        float av_n = __shfl(a_l, gbase);
        uint4 kw_n = *(const uint4*)(kvp + (size_t)src_n * 64);
        for (int j = 0; j < cm; ++j) {
            uint4 kw = kw_n;
            float av = av_n;
            bool valid = j < cnt;
            if (j + 1 < cm) {  // depth-1 prefetch (slots >= cnt hold s_l=0 -> row 0, L2-hot)
                int src1 = __shfl(s_l, gbase + j + 1);
                av_n = __shfl(a_l, gbase + j + 1);
                kw_n = *(const uint4*)(kvp + (size_t)src1 * 64);
            }
            unsigned kd[4] = {kw.x, kw.y, kw.z, kw.w};
            float vj[8];
            float p = 0.f;
#pragma unroll
            for (int t = 0; t < 4; ++t) {
                f32x2 kk = __builtin_amdgcn_cvt_pk_f32_fp8((int)kd[t], false);
                f32x2 vv = __builtin_amdgcn_cvt_pk_f32_fp8((int)kd[t], true);
                p = fmaf(qv[2 * t], kk.x, p);
                p = fmaf(qv[2 * t + 1], kk.y, p);
                vj[2 * t] = vv.x;
                vj[2 * t + 1] = vv.y;
            }
            p += dpp_xor1(p);
            p += dpp_xor2(p);  // head dot (4 lanes = 32 ch)
            p = fmaf(av, qwe, p);
            p = valid ? p : -3e38f;
            if (__any(p - m > THR)) {  // rare: max update + rescale (always taken on first edge)
                float mn2 = fmaxf(m, p);
                float wgt = exp2f(p - mn2);
                float sc = exp2f(m - mn2);
                sden = fmaf(sden, sc, wgt);
                tacc = fmaf(tacc, sc, wgt * av);
#pragma unroll
                for (int i = 0; i < 8; ++i) acc[i] = fmaf(acc[i], sc, wgt * vj[i]);
                m = mn2;
            } else {  // common path
                float wgt = exp2f(p - m);
                sden += wgt;
                tacc = fmaf(wgt, av, tacc);
#pragma unroll
                for (int i = 0; i < 8; ++i) acc[i] = fmaf(wgt, vj[i], acc[i]);
            }
        }
    }

    // finalize (no cross-subgroup merge: softmax state lives in each head's quad)
    float rden = 1.f / (sden + 1e-16f);
    float o[8];
#pragma unroll
    for (int i = 0; i < 8; ++i) o[i] = fmaf(tacc, wev[i], acc[i]) * rden;

    // ---- fused epilogue in the same 8-ch/lane layout (reduces within 16-lane group) ----
    float x[8];
    {
        uint4 xw = *(const uint4*)(xr32 + (size_t)node * 64 + 4 * lnl);
        unsigned xd[4] = {xw.x, xw.y, xw.z, xw.w};
#pragma unroll
        for (int t = 0; t < 4; ++t) {
            x[2 * t] = bf2f((unsigned short)xd[t]);
            x[2 * t + 1] = bf2f((unsigned short)(xd[t] >> 16));
        }
    }
    float bl = 0.f;
#pragma unroll
    for (int t = 0; t < 2; ++t) {
        float4 w0 = *(const float4*)(Wb + 8 * lnl + 4 * t);
        float4 w1 = *(const float4*)(Wb + 128 + 8 * lnl + 4 * t);
        float4 w2 = *(const float4*)(Wb + 256 + 8 * lnl + 4 * t);
        bl = fmaf(o[4 * t], w0.x, bl); bl = fmaf(o[4 * t + 1], w0.y, bl);
        bl = fmaf(o[4 * t + 2], w0.z, bl); bl = fmaf(o[4 * t + 3], w0.w, bl);
        bl = fmaf(x[4 * t], w1.x, bl); bl = fmaf(x[4 * t + 1], w1.y, bl);
        bl = fmaf(x[4 * t + 2], w1.z, bl); bl = fmaf(x[4 * t + 3], w1.w, bl);
        bl = fmaf(o[4 * t] - x[4 * t], w2.x, bl); bl = fmaf(o[4 * t + 1] - x[4 * t + 1], w2.y, bl);
        bl = fmaf(o[4 * t + 2] - x[4 * t + 2], w2.z, bl); bl = fmaf(o[4 * t + 3] - x[4 * t + 3], w2.w, bl);
    }
    bl = red16(bl);
    float beta = 1.f / (1.f + __expf(-bl));
    float tpre[8];
    {
        uint4 rw = *(const uint4*)(res32 + (size_t)node * 64 + 4 * lnl);
        unsigned rd[4] = {rw.x, rw.y, rw.z, rw.w};
#pragma unroll
        for (int i = 0; i < 8; ++i) {
            float gg = beta * x[i] + (1.f - beta) * o[i];
            gg = 0.5f * gg * (1.f + erff(gg * 0.70710678118654752f));
            float rv = (i & 1) ? bf2f((unsigned short)(rd[i >> 1] >> 16)) : bf2f((unsigned short)rd[i >> 1]);
            tpre[i] = gg + rv;
        }
    }
    float su = 0.f, sq = 0.f;
#pragma unroll
    for (int i = 0; i < 8; ++i) {
        su += tpre[i];
        sq = fmaf(tpre[i], tpre[i], sq);
    }
    su = red16(su);
    sq = red16(sq);
    float mu = su * (1.f / 128.f);
    float var = sq * (1.f / 128.f) - mu * mu;
    float inv = rsqrtf(var + 1e-5f);
    float4 g0 = *(const float4*)(lng + 8 * lnl);
    float4 g1 = *(const float4*)(lng + 8 * lnl + 4);
    float4 b0 = *(const float4*)(lnb + 8 * lnl);
    float4 b1 = *(const float4*)(lnb + 8 * lnl + 4);
    float gg[8] = {g0.x, g0.y, g0.z, g0.w, g1.x, g1.y, g1.z, g1.w};
    float bb[8] = {b0.x, b0.y, b0.z, b0.w, b1.x, b1.y, b1.z, b1.w};
    float ov[8];
#pragma unroll
    for (int i = 0; i < 8; ++i) ov[i] = (tpre[i] - mu) * inv * gg[i] + bb[i];
    if (houtf) {
        float* op = houtf + (size_t)node * 128 + 8 * lnl;
        *(float4*)op = make_float4(ov[0], ov[1], ov[2], ov[3]);
        *(float4*)(op + 4) = make_float4(ov[4], ov[5], ov[6], ov[7]);
    } else {
        unsigned pk[4];
#pragma unroll
        for (int d = 0; d < 4; ++d) pk[d] = packbf(ov[2 * d], ov[2 * d + 1]);
        *(uint4*)(houtb + (size_t)node * 64 + 4 * lnl) = make_uint4(pk[0], pk[1], pk[2], pk[3]);
    }
}

extern "C" void kernel_launch(void* const* d_in, const int* in_sizes, int n_in, void* d_out, int out_size,
                              void* d_ws, size_t ws_size, hipStream_t stream) {
    const float* x = (const float*)d_in[0];
    const int* ei = (const int*)d_in[1];
    const float* ea = (const float*)d_in[2];
    const float* Wi = (const float*)d_in[3];
    const float* bi = (const float*)d_in[4];
    const float* Wq = (const float*)d_in[5];
    const float* bq = (const float*)d_in[6];
    const float* Wk = (const float*)d_in[7];
    const float* bk = (const float*)d_in[8];
    const float* Wv = (const float*)d_in[9];
    const float* bv = (const float*)d_in[10];
    const float* We = (const float*)d_in[11];
    const float* Wskip = (const float*)d_in[12];
    const float* bskip = (const float*)d_in[13];
    const float* Wbeta = (const float*)d_in[14];
    const float* lng = (const float*)d_in[15];
    const float* lnb = (const float*)d_in[16];

    const int* srcp = ei;
    const int* dstp = ei + NEDGES;

    char* p = (char*)d_ws;
    auto alloc = [&](size_t bytes) {
        void* r = (void*)p;
        p += (bytes + 255) & ~(size_t)255;
        return r;
    };
    unsigned* h32 = (unsigned*)alloc((size_t)NNODES * 64 * 4);
    unsigned* q32 = (unsigned*)alloc((size_t)NNODES * 64 * 4);
    unsigned* xr32 = (unsigned*)alloc((size_t)NNODES * 64 * 4);
    unsigned* kv = (unsigned*)alloc((size_t)NNODES * 64 * 4);
    unsigned short* Wit = (unsigned short*)alloc((size_t)DHID * DIN * 2);
    unsigned short* Wt3 = (unsigned short*)alloc((size_t)3 * 512 * DHID * 2);
    int* counts = (int*)alloc((size_t)NNODES * 4);
    int* row_ptr = (int*)alloc((size_t)(NNODES + 1) * 4);
    int2* esrc = (int2*)alloc((size_t)NEDGES * 8);
    int* partials = (int*)alloc(256 * 4);

    const int EB = (NEDGES + 255) / 256;
    const int NB = (NNODES + 255) / 256;
    const int GB = (NNODES + 127) / 128;  // 391
    const int WB = NNODES / 16;           // 3125 (16 nodes/block, 4 per wave)
    const int PB = (DHID * DIN + 3 * 512 * DHID + 255) / 256;

    prep_w<<<PB, 256, 0, stream>>>(Wi, Wq, Wk, Wv, Wskip, Wit, Wt3);

    // CSR by dst (single memset; scatter consumes the degree histogram via atomicSub)
    hipMemsetAsync(counts, 0, (size_t)NNODES * 4, stream);
    k_hist<<<EB, 256, 0, stream>>>(dstp, counts);
    k_scan_block<<<NB, 256, 0, stream>>>(counts, row_ptr + 1, partials, NNODES);
    k_apply2<<<NB, 256, 0, stream>>>(partials, row_ptr, NNODES, NB);
    k_scatter<<<EB, 256, 0, stream>>>(srcp, dstp, ea, row_ptr, counts, esrc);

    gemm_in<<<GB, 256, 0, stream>>>(x, Wit, bi, h32, NNODES);

    for (int l = 0; l < 3; ++l) {
        const size_t bo = (size_t)l * 128;
        gemm_qkvs<<<GB, 512, 0, stream>>>((const unsigned short*)h32, Wt3 + (size_t)l * 512 * DHID, bq + bo, bk + bo,
                                          bv + bo, bskip + bo, q32, kv, xr32, NNODES);
        node_attn_fuse<<<WB, 256, 0, stream>>>(q32, kv, esrc, We + bo, row_ptr, xr32, h32,
                                               Wbeta + (size_t)l * 384, lng + bo, lnb + bo, h32,
                                               (l == 2) ? (float*)d_out : nullptr);
    }
}

// Round 11
// 325.847 us; speedup vs baseline: 1.2961x; 1.0140x over previous
//
#include <hip/hip_runtime.h>
#include <math.h>

#define NNODES 50000
#define NEDGES 800000
#define DIN 256
#define DHID 128
#define GBLK 391  // gemm row blocks = ceil(50000/128)

typedef __attribute__((ext_vector_type(8))) short short8;
typedef __attribute__((ext_vector_type(4))) float f32x4;
typedef __attribute__((ext_vector_type(2))) float f32x2;

__device__ __forceinline__ unsigned short f2bf(float f) {
    unsigned u = __builtin_bit_cast(unsigned, f);
    u += 0x7fffu + ((u >> 16) & 1u);  // RNE
    return (unsigned short)(u >> 16);
}
__device__ __forceinline__ float bf2f(unsigned short s) {
    return __builtin_bit_cast(float, (unsigned)s << 16);
}
__device__ __forceinline__ unsigned packbf(float a, float b) {
    return (unsigned)f2bf(a) | ((unsigned)f2bf(b) << 16);
}
// DPP helpers: full-rate VALU cross-lane (no LDS)
__device__ __forceinline__ float dpp_xor1(float x) {  // quad_perm [1,0,3,2]
    return __builtin_bit_cast(float, __builtin_amdgcn_update_dpp(0, __builtin_bit_cast(int, x), 0xB1, 0xF, 0xF, true));
}
__device__ __forceinline__ float dpp_xor2(float x) {  // quad_perm [2,3,0,1]
    return __builtin_bit_cast(float, __builtin_amdgcn_update_dpp(0, __builtin_bit_cast(int, x), 0x4E, 0xF, 0xF, true));
}
__device__ __forceinline__ float dpp_hmirror(float x) {  // row_half_mirror
    return __builtin_bit_cast(float, __builtin_amdgcn_update_dpp(0, __builtin_bit_cast(int, x), 0x141, 0xF, 0xF, true));
}
__device__ __forceinline__ float dpp_mirror(float x) {  // row_mirror
    return __builtin_bit_cast(float, __builtin_amdgcn_update_dpp(0, __builtin_bit_cast(int, x), 0x140, 0xF, 0xF, true));
}
__device__ __forceinline__ float red16(float x) {
    x += dpp_xor1(x);
    x += dpp_xor2(x);
    x += dpp_hmirror(x);
    x += dpp_mirror(x);
    return x;
}

// ---------------- weight prep (blocks < PB) + degree histogram (blocks >= PB) ----------------
__global__ __launch_bounds__(256) void prep_hist(const float* __restrict__ Wi, const float* __restrict__ Wq,
                                                 const float* __restrict__ Wk, const float* __restrict__ Wv,
                                                 const float* __restrict__ Ws, unsigned short* __restrict__ Wit,
                                                 unsigned short* __restrict__ Wt3, const int* __restrict__ dst,
                                                 int* __restrict__ counts, int pb) {
    if ((int)blockIdx.x < pb) {
        int idx = blockIdx.x * 256 + threadIdx.x;
        if (idx < DHID * DIN) {
            int n = idx >> 8, kk = idx & 255;
            Wit[idx] = f2bf(Wi[kk * DHID + n]);
        }
        int idx2 = idx - DHID * DIN;
        if (idx2 >= 0 && idx2 < 3 * 512 * DHID) {
            int l = idx2 / (512 * DHID);
            int rem = idx2 - l * 512 * DHID;
            int r = rem >> 7;
            int kk = rem & 127;
            int sel = r >> 7, rl = r & 127;
            const float* srcm = sel == 0 ? Wq : sel == 1 ? Wk : sel == 2 ? Wv : Ws;
            Wt3[idx2] = f2bf(srcm[l * DHID * DHID + kk * DHID + rl]);
        }
    } else {
        int e = (blockIdx.x - pb) * 256 + threadIdx.x;
        if (e < NEDGES) atomicAdd(&counts[dst[e]], 1);
    }
}

__global__ __launch_bounds__(256) void k_scan_block(const int* __restrict__ in, int* __restrict__ out,
                                                    int* __restrict__ partials, int n) {
    __shared__ int sh[256];
    int tid = threadIdx.x;
    int i = blockIdx.x * 256 + tid;
    int vv = (i < n) ? in[i] : 0;
    sh[tid] = vv;
    __syncthreads();
    for (int off = 1; off < 256; off <<= 1) {
        int t = (tid >= off) ? sh[tid - off] : 0;
        __syncthreads();
        sh[tid] += t;
        __syncthreads();
    }
    if (i < n) out[i] = sh[tid];
    if (tid == 255) partials[blockIdx.x] = sh[255];
}

// every block locally scans the (<=256) partials, then applies its prefix
__global__ __launch_bounds__(256) void k_apply2(const int* __restrict__ partials, int* __restrict__ row_ptr, int n,
                                                int nb) {
    __shared__ int sh[256];
    int tid = threadIdx.x;
    int vv = (tid < nb) ? partials[tid] : 0;
    sh[tid] = vv;
    __syncthreads();
    for (int off = 1; off < 256; off <<= 1) {
        int t = (tid >= off) ? sh[tid - off] : 0;
        __syncthreads();
        sh[tid] += t;
        __syncthreads();
    }
    int i = blockIdx.x * 256 + tid;
    if (i < n) {
        int add = blockIdx.x ? sh[blockIdx.x - 1] : 0;
        row_ptr[i + 1] += add;
    }
    if (i == 0) row_ptr[0] = 0;
}

// ---------------- merged: input-projection GEMM (blocks < GBLK) + edge scatter (blocks >= GBLK) ----------------
// gemm: h[M,128](bf16) = x[M,256] @ Wi + bi.  scatter: dst-sorted packed (src:16|ea_bf16:16), nontemporal 4B stores.
__global__ __launch_bounds__(256) void scatter_gemm(const float* __restrict__ A, const unsigned short* __restrict__ Wt,
                                                    const float* __restrict__ bias, unsigned* __restrict__ h32, int M,
                                                    const int* __restrict__ src, const int* __restrict__ dst,
                                                    const float* __restrict__ ea, const int* __restrict__ row_ptr,
                                                    int* __restrict__ fill, unsigned* __restrict__ esrc) {
    __shared__ short As[128 * 128];
    const int tid = threadIdx.x;
    if ((int)blockIdx.x >= GBLK) {
        int e = (blockIdx.x - GBLK) * 256 + tid;
        if (e < NEDGES) {
            int d = dst[e];
            int old = atomicSub(&fill[d], 1);
            int pos = row_ptr[d] + old - 1;
            unsigned pk = (unsigned)src[e] | ((unsigned)f2bf(ea[e]) << 16);
            __builtin_nontemporal_store(pk, &esrc[pos]);
        }
        return;
    }
    const int lane = tid & 63;
    const int wid = tid >> 6;
    const int row0 = blockIdx.x * 128;
    const int wr = (wid & 1) * 64;
    const int wc = (wid >> 1) * 64;
    f32x4 acc[4][4] = {};
    const int srow = tid >> 1;
    const int sk = (tid & 1) * 64;
    const int grow = min(row0 + srow, M - 1);
    for (int kt = 0; kt < 2; ++kt) {
        const float* ap = A + (size_t)grow * DIN + kt * 128 + sk;
#pragma unroll
        for (int i = 0; i < 8; ++i) {
            float4 f0 = *(const float4*)(ap + i * 8);
            float4 f1 = *(const float4*)(ap + i * 8 + 4);
            short8 s;
            s[0] = f2bf(f0.x); s[1] = f2bf(f0.y); s[2] = f2bf(f0.z); s[3] = f2bf(f0.w);
            s[4] = f2bf(f1.x); s[5] = f2bf(f1.y); s[6] = f2bf(f1.z); s[7] = f2bf(f1.w);
            int g = (sk >> 3) + i;
            *(short8*)(&As[srow * 128 + ((g ^ (srow & 7)) << 3)]) = s;
        }
        __syncthreads();
#pragma unroll
        for (int ks = 0; ks < 4; ++ks) {
            short8 a[4], b[4];
#pragma unroll
            for (int m = 0; m < 4; ++m) {
                int r = wr + m * 16 + (lane & 15);
                int g = ks * 4 + (lane >> 4);
                a[m] = *(const short8*)(&As[r * 128 + ((g ^ (r & 7)) << 3)]);
            }
#pragma unroll
            for (int n = 0; n < 4; ++n) {
                int c = wc + n * 16 + (lane & 15);
                b[n] = *(const short8*)(Wt + (size_t)c * DIN + kt * 128 + ks * 32 + (lane >> 4) * 8);
            }
#pragma unroll
            for (int m = 0; m < 4; ++m)
#pragma unroll
                for (int n = 0; n < 4; ++n)
                    acc[m][n] = __builtin_amdgcn_mfma_f32_16x16x32_bf16(a[m], b[n], acc[m][n], 0, 0, 0);
        }
        __syncthreads();
    }
    // epilogue: per-wave LDS repack (reuse As) -> coalesced uint4 stores
    float* my = ((float*)As) + wid * 1024;
    float bb[4];
#pragma unroll
    for (int n = 0; n < 4; ++n) bb[n] = bias[wc + n * 16 + (lane & 15)];
    const int rr = lane >> 2;
    const int cb = lane & 3;
#pragma unroll
    for (int m = 0; m < 4; ++m) {
#pragma unroll
        for (int n = 0; n < 4; ++n) {
            int lc = n * 16 + (lane & 15);
#pragma unroll
            for (int j = 0; j < 4; ++j) {
                int row = (lane >> 4) * 4 + j;
                my[row * 64 + (((lc >> 2) ^ (row & 7)) << 2) + (lc & 3)] = acc[m][n][j] + bb[n];
            }
        }
        float vals[16];
#pragma unroll
        for (int s = 0; s < 4; ++s) {
            int gx = (cb * 4 + s) ^ (rr & 7);
            f32x4 t4 = *(const f32x4*)(my + rr * 64 + gx * 4);
            vals[s * 4 + 0] = t4.x; vals[s * 4 + 1] = t4.y; vals[s * 4 + 2] = t4.z; vals[s * 4 + 3] = t4.w;
        }
        int grow2 = row0 + wr + m * 16 + rr;
        if (grow2 < M) {
            unsigned pk[8];
#pragma unroll
            for (int d = 0; d < 8; ++d) pk[d] = packbf(vals[2 * d], vals[2 * d + 1]);
            unsigned* op = h32 + (size_t)grow2 * 64 + (wc >> 1) + cb * 8;
            *(uint4*)op = make_uint4(pk[0], pk[1], pk[2], pk[3]);
            *(uint4*)(op + 4) = make_uint4(pk[4], pk[5], pk[6], pk[7]);
        }
    }
}

// ---------------- fused q/k/v/skip GEMM from bf16 h ----------------
__global__ __launch_bounds__(512) void gemm_qkvs(const unsigned short* __restrict__ A,
                                                 const unsigned short* __restrict__ Wt, const float* __restrict__ bq,
                                                 const float* __restrict__ bk, const float* __restrict__ bv,
                                                 const float* __restrict__ bs, unsigned* __restrict__ q32,
                                                 unsigned* __restrict__ kv, unsigned* __restrict__ xr32, int M) {
    __shared__ short As[128 * 128];
    const int tid = threadIdx.x;
    const int lane = tid & 63;
    const int wid = tid >> 6;
    const int row0 = blockIdx.x * 128;
    const int sel = wid >> 2;  // 0: q/skip, 1: k/v
    const int wr = (wid & 1) * 64;
    const int wc = ((wid >> 1) & 1) * 64;
    f32x4 acc0[4][4] = {}, acc1[4][4] = {};
    {
        const int srow = tid >> 2;
        const int sk = (tid & 3) * 32;
        const int grow = min(row0 + srow, M - 1);
        const unsigned short* ap = A + (size_t)grow * DHID + sk;
#pragma unroll
        for (int i = 0; i < 4; ++i) {
            short8 s = *(const short8*)(ap + i * 8);
            int g = (sk >> 3) + i;
            *(short8*)(&As[srow * 128 + ((g ^ (srow & 7)) << 3)]) = s;
        }
    }
    __syncthreads();
    const int b0base = sel ? 128 : 0;    // k : q
    const int b1base = sel ? 256 : 384;  // v : skip
#pragma unroll
    for (int ks = 0; ks < 4; ++ks) {
        short8 a[4], b0[4], b1[4];
#pragma unroll
        for (int m = 0; m < 4; ++m) {
            int r = wr + m * 16 + (lane & 15);
            int g = ks * 4 + (lane >> 4);
            a[m] = *(const short8*)(&As[r * 128 + ((g ^ (r & 7)) << 3)]);
        }
#pragma unroll
        for (int n = 0; n < 4; ++n) {
            int rb = wc + n * 16 + (lane & 15);
            b0[n] = *(const short8*)(Wt + (size_t)(b0base + rb) * DHID + ks * 32 + (lane >> 4) * 8);
            b1[n] = *(const short8*)(Wt + (size_t)(b1base + rb) * DHID + ks * 32 + (lane >> 4) * 8);
        }
#pragma unroll
        for (int m = 0; m < 4; ++m)
#pragma unroll
            for (int n = 0; n < 4; ++n) {
                acc0[m][n] = __builtin_amdgcn_mfma_f32_16x16x32_bf16(a[m], b0[n], acc0[m][n], 0, 0, 0);
                acc1[m][n] = __builtin_amdgcn_mfma_f32_16x16x32_bf16(a[m], b1[n], acc1[m][n], 0, 0, 0);
            }
    }
    __syncthreads();  // done reading As; reuse as repack buffer
    float* my = ((float*)As) + wid * 1024;
    const float* bias0 = sel ? bk : bq;
    const float* bias1 = sel ? bv : bs;
    float bb0[4], bb1[4];
#pragma unroll
    for (int n = 0; n < 4; ++n) {
        int c = wc + n * 16 + (lane & 15);
        bb0[n] = bias0[c];
        bb1[n] = bias1[c];
    }
    const int rr = lane >> 2;
    const int cb = lane & 3;
#pragma unroll
    for (int m = 0; m < 4; ++m) {
        float vals0[16], vals1[16];
#pragma unroll
        for (int n = 0; n < 4; ++n) {
            int lc = n * 16 + (lane & 15);
#pragma unroll
            for (int j = 0; j < 4; ++j) {
                int row = (lane >> 4) * 4 + j;
                my[row * 64 + (((lc >> 2) ^ (row & 7)) << 2) + (lc & 3)] = acc0[m][n][j] + bb0[n];
            }
        }
#pragma unroll
        for (int s = 0; s < 4; ++s) {
            int gx = (cb * 4 + s) ^ (rr & 7);
            f32x4 t4 = *(const f32x4*)(my + rr * 64 + gx * 4);
            vals0[s * 4 + 0] = t4.x; vals0[s * 4 + 1] = t4.y; vals0[s * 4 + 2] = t4.z; vals0[s * 4 + 3] = t4.w;
        }
#pragma unroll
        for (int n = 0; n < 4; ++n) {
            int lc = n * 16 + (lane & 15);
#pragma unroll
            for (int j = 0; j < 4; ++j) {
                int row = (lane >> 4) * 4 + j;
                my[row * 64 + (((lc >> 2) ^ (row & 7)) << 2) + (lc & 3)] = acc1[m][n][j] + bb1[n];
            }
        }
#pragma unroll
        for (int s = 0; s < 4; ++s) {
            int gx = (cb * 4 + s) ^ (rr & 7);
            f32x4 t4 = *(const f32x4*)(my + rr * 64 + gx * 4);
            vals1[s * 4 + 0] = t4.x; vals1[s * 4 + 1] = t4.y; vals1[s * 4 + 2] = t4.z; vals1[s * 4 + 3] = t4.w;
        }
        int grow2 = row0 + wr + m * 16 + rr;
        if (grow2 < M) {
            size_t obase = (size_t)grow2 * 64 + (wc >> 1) + cb * 8;
            if (sel == 0) {
                unsigned p0[8], p1[8];
#pragma unroll
                for (int d = 0; d < 8; ++d) {
                    p0[d] = packbf(vals0[2 * d], vals0[2 * d + 1]);
                    p1[d] = packbf(vals1[2 * d], vals1[2 * d + 1]);
                }
                *(uint4*)(q32 + obase) = make_uint4(p0[0], p0[1], p0[2], p0[3]);
                *(uint4*)(q32 + obase + 4) = make_uint4(p0[4], p0[5], p0[6], p0[7]);
                *(uint4*)(xr32 + obase) = make_uint4(p1[0], p1[1], p1[2], p1[3]);
                *(uint4*)(xr32 + obase + 4) = make_uint4(p1[4], p1[5], p1[6], p1[7]);
            } else {
                unsigned pk[8];
#pragma unroll
                for (int d = 0; d < 8; ++d) {
                    unsigned u = (unsigned)__builtin_amdgcn_cvt_pk_fp8_f32(vals0[2 * d], vals0[2 * d + 1], 0, false);
                    u = (unsigned)__builtin_amdgcn_cvt_pk_fp8_f32(vals1[2 * d], vals1[2 * d + 1], (int)u, true);
                    pk[d] = u;
                }
                *(uint4*)(kv + obase) = make_uint4(pk[0], pk[1], pk[2], pk[3]);
                *(uint4*)(kv + obase + 4) = make_uint4(pk[4], pk[5], pk[6], pk[7]);
            }
        }
    }
}

// ---------------- per-node attention + beta-gate + GELU + LayerNorm ----------------
// 4 nodes per wave: 16-lane group per node, lane owns 8 consecutive channels (4 kv dwords = 1 uint4).
// Meta = packed (src:16 | ea_bf16:16); one __shfl broadcast per edge. Depth-1 kv prefetch. Zero LDS.
// Algebra: logit = q·k + av*(q·we);  out = (Σw·v + (Σw·av)·we)/Σw. exp2-domain, defer-max.
// houtb may alias res32 (same-wave RAW only).
__global__ __launch_bounds__(256) void node_attn_fuse(const unsigned* __restrict__ q32,
                                                      const unsigned* __restrict__ kv, const unsigned* __restrict__ esrc,
                                                      const float* __restrict__ We, const int* __restrict__ row_ptr,
                                                      const unsigned* __restrict__ xr32, const unsigned* res32,
                                                      const float* __restrict__ Wb, const float* __restrict__ lng,
                                                      const float* __restrict__ lnb, unsigned* houtb, float* houtf) {
    const int tid = threadIdx.x;
    const int lane = tid & 63;
    const int lnl = lane & 15;   // lane within node group
    const int gbase = lane & 48; // group base lane
    const int node = blockIdx.x * 16 + (tid >> 4);  // 16 nodes per block; 50000 = 3125*16 exact
    const int base = row_ptr[node], end = row_ptr[node + 1];
    const float SC = 0.25505654047688565f;  // (1/sqrt(32)) * log2(e)
    const float THR = 8.0f;

    float qv[8], wev[8];
    {
        uint4 qw = *(const uint4*)(q32 + (size_t)node * 64 + 4 * lnl);
        unsigned qd[4] = {qw.x, qw.y, qw.z, qw.w};
#pragma unroll
        for (int t = 0; t < 4; ++t) {
            qv[2 * t] = bf2f((unsigned short)qd[t]) * SC;
            qv[2 * t + 1] = bf2f((unsigned short)(qd[t] >> 16)) * SC;
        }
        float4 wlo = *(const float4*)(We + 8 * lnl);
        float4 whi = *(const float4*)(We + 8 * lnl + 4);
        wev[0] = wlo.x; wev[1] = wlo.y; wev[2] = wlo.z; wev[3] = wlo.w;
        wev[4] = whi.x; wev[5] = whi.y; wev[6] = whi.z; wev[7] = whi.w;
    }
    float qwe;
    {
        float s = 0.f;
#pragma unroll
        for (int i = 0; i < 8; ++i) s = fmaf(qv[i], wev[i], s);
        s += dpp_xor1(s);
        s += dpp_xor2(s);
        qwe = s;
    }

    float m = -1e30f, sden = 0.f, tacc = 0.f;
    float acc[8] = {};
    const unsigned* kvp = kv + 4 * lnl;

    for (int off = 0; ; off += 16) {
        int cnt = min(end - base - off, 16);  // per-group; may be <= 0
        if (__all(cnt <= 0)) break;
        unsigned u_l = 0;
        if (lnl < cnt) u_l = esrc[base + off + lnl];
        int cm = max(cnt, 0);
        cm = max(cm, __shfl_xor(cm, 16));
        cm = max(cm, __shfl_xor(cm, 32));
        // prefetch j=0
        unsigned ue_n = __shfl((int)u_l, gbase);
        uint4 kw_n = *(const uint4*)(kvp + (size_t)(ue_n & 0xFFFFu) * 64);
        for (int j = 0; j < cm; ++j) {
            uint4 kw = kw_n;
            float av = bf2f((unsigned short)(ue_n >> 16));
            bool valid = j < cnt;
            if (j + 1 < cm) {  // depth-1 prefetch (padding slots -> row 0, L2-hot)
                ue_n = __shfl((int)u_l, gbase + j + 1);
                kw_n = *(const uint4*)(kvp + (size_t)(ue_n & 0xFFFFu) * 64);
            }
            unsigned kd[4] = {kw.x, kw.y, kw.z, kw.w};
            float vj[8];
            float p = 0.f;
#pragma unroll
            for (int t = 0; t < 4; ++t) {
                f32x2 kk = __builtin_amdgcn_cvt_pk_f32_fp8((int)kd[t], false);
                f32x2 vv = __builtin_amdgcn_cvt_pk_f32_fp8((int)kd[t], true);
                p = fmaf(qv[2 * t], kk.x, p);
                p = fmaf(qv[2 * t + 1], kk.y, p);
                vj[2 * t] = vv.x;
                vj[2 * t + 1] = vv.y;
            }
            p += dpp_xor1(p);
            p += dpp_xor2(p);  // head dot (4 lanes = 32 ch)
            p = fmaf(av, qwe, p);
            p = valid ? p : -3e38f;
            if (__any(p - m > THR)) {  // rare: max update + rescale (taken on first edge)
                float mn2 = fmaxf(m, p);
                float wgt = exp2f(p - mn2);
                float sc = exp2f(m - mn2);
                sden = fmaf(sden, sc, wgt);
                tacc = fmaf(tacc, sc, wgt * av);
#pragma unroll
                for (int i = 0; i < 8; ++i) acc[i] = fmaf(acc[i], sc, wgt * vj[i]);
                m = mn2;
            } else {  // common path
                float wgt = exp2f(p - m);
                sden += wgt;
                tacc = fmaf(wgt, av, tacc);
#pragma unroll
                for (int i = 0; i < 8; ++i) acc[i] = fmaf(wgt, vj[i], acc[i]);
            }
        }
    }

    float rden = 1.f / (sden + 1e-16f);
    float o[8];
#pragma unroll
    for (int i = 0; i < 8; ++i) o[i] = fmaf(tacc, wev[i], acc[i]) * rden;

    // ---- fused epilogue in the same 8-ch/lane layout (reduces within 16-lane group) ----
    float x[8];
    {
        uint4 xw = *(const uint4*)(xr32 + (size_t)node * 64 + 4 * lnl);
        unsigned xd[4] = {xw.x, xw.y, xw.z, xw.w};
#pragma unroll
        for (int t = 0; t < 4; ++t) {
            x[2 * t] = bf2f((unsigned short)xd[t]);
            x[2 * t + 1] = bf2f((unsigned short)(xd[t] >> 16));
        }
    }
    float bl = 0.f;
#pragma unroll
    for (int t = 0; t < 2; ++t) {
        float4 w0 = *(const float4*)(Wb + 8 * lnl + 4 * t);
        float4 w1 = *(const float4*)(Wb + 128 + 8 * lnl + 4 * t);
        float4 w2 = *(const float4*)(Wb + 256 + 8 * lnl + 4 * t);
        bl = fmaf(o[4 * t], w0.x, bl); bl = fmaf(o[4 * t + 1], w0.y, bl);
        bl = fmaf(o[4 * t + 2], w0.z, bl); bl = fmaf(o[4 * t + 3], w0.w, bl);
        bl = fmaf(x[4 * t], w1.x, bl); bl = fmaf(x[4 * t + 1], w1.y, bl);
        bl = fmaf(x[4 * t + 2], w1.z, bl); bl = fmaf(x[4 * t + 3], w1.w, bl);
        bl = fmaf(o[4 * t] - x[4 * t], w2.x, bl); bl = fmaf(o[4 * t + 1] - x[4 * t + 1], w2.y, bl);
        bl = fmaf(o[4 * t + 2] - x[4 * t + 2], w2.z, bl); bl = fmaf(o[4 * t + 3] - x[4 * t + 3], w2.w, bl);
    }
    bl = red16(bl);
    float beta = 1.f / (1.f + __expf(-bl));
    float tpre[8];
    {
        uint4 rw = *(const uint4*)(res32 + (size_t)node * 64 + 4 * lnl);
        unsigned rd[4] = {rw.x, rw.y, rw.z, rw.w};
#pragma unroll
        for (int i = 0; i < 8; ++i) {
            float gg = beta * x[i] + (1.f - beta) * o[i];
            gg = 0.5f * gg * (1.f + erff(gg * 0.70710678118654752f));
            float rv = (i & 1) ? bf2f((unsigned short)(rd[i >> 1] >> 16)) : bf2f((unsigned short)rd[i >> 1]);
            tpre[i] = gg + rv;
        }
    }
    float su = 0.f, sq = 0.f;
#pragma unroll
    for (int i = 0; i < 8; ++i) {
        su += tpre[i];
        sq = fmaf(tpre[i], tpre[i], sq);
    }
    su = red16(su);
    sq = red16(sq);
    float mu = su * (1.f / 128.f);
    float var = sq * (1.f / 128.f) - mu * mu;
    float inv = rsqrtf(var + 1e-5f);
    float4 g0 = *(const float4*)(lng + 8 * lnl);
    float4 g1 = *(const float4*)(lng + 8 * lnl + 4);
    float4 b0 = *(const float4*)(lnb + 8 * lnl);
    float4 b1 = *(const float4*)(lnb + 8 * lnl + 4);
    float gg[8] = {g0.x, g0.y, g0.z, g0.w, g1.x, g1.y, g1.z, g1.w};
    float bb[8] = {b0.x, b0.y, b0.z, b0.w, b1.x, b1.y, b1.z, b1.w};
    float ov[8];
#pragma unroll
    for (int i = 0; i < 8; ++i) ov[i] = (tpre[i] - mu) * inv * gg[i] + bb[i];
    if (houtf) {
        float* op = houtf + (size_t)node * 128 + 8 * lnl;
        *(float4*)op = make_float4(ov[0], ov[1], ov[2], ov[3]);
        *(float4*)(op + 4) = make_float4(ov[4], ov[5], ov[6], ov[7]);
    } else {
        unsigned pk[4];
#pragma unroll
        for (int d = 0; d < 4; ++d) pk[d] = packbf(ov[2 * d], ov[2 * d + 1]);
        *(uint4*)(houtb + (size_t)node * 64 + 4 * lnl) = make_uint4(pk[0], pk[1], pk[2], pk[3]);
    }
}

extern "C" void kernel_launch(void* const* d_in, const int* in_sizes, int n_in, void* d_out, int out_size,
                              void* d_ws, size_t ws_size, hipStream_t stream) {
    const float* x = (const float*)d_in[0];
    const int* ei = (const int*)d_in[1];
    const float* ea = (const float*)d_in[2];
    const float* Wi = (const float*)d_in[3];
    const float* bi = (const float*)d_in[4];
    const float* Wq = (const float*)d_in[5];
    const float* bq = (const float*)d_in[6];
    const float* Wk = (const float*)d_in[7];
    const float* bk = (const float*)d_in[8];
    const float* Wv = (const float*)d_in[9];
    const float* bv = (const float*)d_in[10];
    const float* We = (const float*)d_in[11];
    const float* Wskip = (const float*)d_in[12];
    const float* bskip = (const float*)d_in[13];
    const float* Wbeta = (const float*)d_in[14];
    const float* lng = (const float*)d_in[15];
    const float* lnb = (const float*)d_in[16];

    const int* srcp = ei;
    const int* dstp = ei + NEDGES;

    char* p = (char*)d_ws;
    auto alloc = [&](size_t bytes) {
        void* r = (void*)p;
        p += (bytes + 255) & ~(size_t)255;
        return r;
    };
    unsigned* h32 = (unsigned*)alloc((size_t)NNODES * 64 * 4);
    unsigned* q32 = (unsigned*)alloc((size_t)NNODES * 64 * 4);
    unsigned* xr32 = (unsigned*)alloc((size_t)NNODES * 64 * 4);
    unsigned* kv = (unsigned*)alloc((size_t)NNODES * 64 * 4);
    unsigned short* Wit = (unsigned short*)alloc((size_t)DHID * DIN * 2);
    unsigned short* Wt3 = (unsigned short*)alloc((size_t)3 * 512 * DHID * 2);
    int* counts = (int*)alloc((size_t)NNODES * 4);
    int* row_ptr = (int*)alloc((size_t)(NNODES + 1) * 4);
    unsigned* esrc = (unsigned*)alloc((size_t)NEDGES * 4);
    int* partials = (int*)alloc(256 * 4);

    const int EB = (NEDGES + 255) / 256;  // 3125
    const int NB = (NNODES + 255) / 256;  // 196
    const int WB = NNODES / 16;           // 3125
    const int PB = (DHID * DIN + 3 * 512 * DHID + 255) / 256;  // 896

    // counts zeroed; prep (weights) + degree histogram in one kernel
    hipMemsetAsync(counts, 0, (size_t)NNODES * 4, stream);
    prep_hist<<<PB + EB, 256, 0, stream>>>(Wi, Wq, Wk, Wv, Wskip, Wit, Wt3, dstp, counts, PB);
    k_scan_block<<<NB, 256, 0, stream>>>(counts, row_ptr + 1, partials, NNODES);
    k_apply2<<<NB, 256, 0, stream>>>(partials, row_ptr, NNODES, NB);
    // input-projection GEMM + edge scatter fused (independent; overlap compute with scattered writes)
    scatter_gemm<<<GBLK + EB, 256, 0, stream>>>(x, Wit, bi, h32, NNODES, srcp, dstp, ea, row_ptr, counts, esrc);

    for (int l = 0; l < 3; ++l) {
        const size_t bo = (size_t)l * 128;
        gemm_qkvs<<<GBLK, 512, 0, stream>>>((const unsigned short*)h32, Wt3 + (size_t)l * 512 * DHID, bq + bo, bk + bo,
                                            bv + bo, bskip + bo, q32, kv, xr32, NNODES);
        node_attn_fuse<<<WB, 256, 0, stream>>>(q32, kv, esrc, We + bo, row_ptr, xr32, h32,
                                               Wbeta + (size_t)l * 384, lng + bo, lnb + bo, h32,
                                               (l == 2) ? (float*)d_out : nullptr);
    }
}

// Round 12
// 312.711 us; speedup vs baseline: 1.3505x; 1.0420x over previous
//
#include <hip/hip_runtime.h>
#include <math.h>

#define NNODES 50000
#define NEDGES 800000
#define DIN 256
#define DHID 128
#define GBLK 391   // gemm row blocks = ceil(50000/128)
#define NBUCK 196  // ceil(50000/256) dst buckets
#define CHUNK 4096 // edges per bin_edges block

typedef __attribute__((ext_vector_type(8))) short short8;
typedef __attribute__((ext_vector_type(4))) float f32x4;
typedef __attribute__((ext_vector_type(2))) float f32x2;

__device__ __forceinline__ unsigned short f2bf(float f) {
    unsigned u = __builtin_bit_cast(unsigned, f);
    u += 0x7fffu + ((u >> 16) & 1u);  // RNE
    return (unsigned short)(u >> 16);
}
__device__ __forceinline__ float bf2f(unsigned short s) {
    return __builtin_bit_cast(float, (unsigned)s << 16);
}
__device__ __forceinline__ unsigned packbf(float a, float b) {
    return (unsigned)f2bf(a) | ((unsigned)f2bf(b) << 16);
}
// DPP helpers: full-rate VALU cross-lane (no LDS)
__device__ __forceinline__ float dpp_xor1(float x) {  // quad_perm [1,0,3,2]
    return __builtin_bit_cast(float, __builtin_amdgcn_update_dpp(0, __builtin_bit_cast(int, x), 0xB1, 0xF, 0xF, true));
}
__device__ __forceinline__ float dpp_xor2(float x) {  // quad_perm [2,3,0,1]
    return __builtin_bit_cast(float, __builtin_amdgcn_update_dpp(0, __builtin_bit_cast(int, x), 0x4E, 0xF, 0xF, true));
}
__device__ __forceinline__ float dpp_hmirror(float x) {  // row_half_mirror
    return __builtin_bit_cast(float, __builtin_amdgcn_update_dpp(0, __builtin_bit_cast(int, x), 0x141, 0xF, 0xF, true));
}
__device__ __forceinline__ float dpp_mirror(float x) {  // row_mirror
    return __builtin_bit_cast(float, __builtin_amdgcn_update_dpp(0, __builtin_bit_cast(int, x), 0x140, 0xF, 0xF, true));
}
__device__ __forceinline__ float red16(float x) {
    x += dpp_xor1(x);
    x += dpp_xor2(x);
    x += dpp_hmirror(x);
    x += dpp_mirror(x);
    return x;
}

// ---------------- weight prep (blocks < pb) + degree histogram (blocks >= pb) ----------------
__global__ __launch_bounds__(256) void prep_hist(const float* __restrict__ Wi, const float* __restrict__ Wq,
                                                 const float* __restrict__ Wk, const float* __restrict__ Wv,
                                                 const float* __restrict__ Ws, unsigned short* __restrict__ Wit,
                                                 unsigned short* __restrict__ Wt3, const int* __restrict__ dst,
                                                 int* __restrict__ counts, int pb) {
    if ((int)blockIdx.x < pb) {
        int idx = blockIdx.x * 256 + threadIdx.x;
        if (idx < DHID * DIN) {
            int n = idx >> 8, kk = idx & 255;
            Wit[idx] = f2bf(Wi[kk * DHID + n]);
        }
        int idx2 = idx - DHID * DIN;
        if (idx2 >= 0 && idx2 < 3 * 512 * DHID) {
            int l = idx2 / (512 * DHID);
            int rem = idx2 - l * 512 * DHID;
            int r = rem >> 7;
            int kk = rem & 127;
            int sel = r >> 7, rl = r & 127;
            const float* srcm = sel == 0 ? Wq : sel == 1 ? Wk : sel == 2 ? Wv : Ws;
            Wt3[idx2] = f2bf(srcm[l * DHID * DHID + kk * DHID + rl]);
        }
    } else {
        int e = (blockIdx.x - pb) * 256 + threadIdx.x;
        if (e < NEDGES) atomicAdd(&counts[dst[e]], 1);
    }
}

__global__ __launch_bounds__(256) void k_scan_block(const int* __restrict__ in, int* __restrict__ out,
                                                    int* __restrict__ partials, int n) {
    __shared__ int sh[256];
    int tid = threadIdx.x;
    int i = blockIdx.x * 256 + tid;
    int vv = (i < n) ? in[i] : 0;
    sh[tid] = vv;
    __syncthreads();
    for (int off = 1; off < 256; off <<= 1) {
        int t = (tid >= off) ? sh[tid - off] : 0;
        __syncthreads();
        sh[tid] += t;
        __syncthreads();
    }
    if (i < n) out[i] = sh[tid];
    if (tid == 255) partials[blockIdx.x] = sh[255];
}

// every block locally scans the (<=256) partials, then applies its prefix
__global__ __launch_bounds__(256) void k_apply2(const int* __restrict__ partials, int* __restrict__ row_ptr, int n,
                                                int nb) {
    __shared__ int sh[256];
    int tid = threadIdx.x;
    int vv = (tid < nb) ? partials[tid] : 0;
    sh[tid] = vv;
    __syncthreads();
    for (int off = 1; off < 256; off <<= 1) {
        int t = (tid >= off) ? sh[tid - off] : 0;
        __syncthreads();
        sh[tid] += t;
        __syncthreads();
    }
    int i = blockIdx.x * 256 + tid;
    if (i < n) {
        int add = blockIdx.x ? sh[blockIdx.x - 1] : 0;
        row_ptr[i + 1] += add;
    }
    if (i == 0) row_ptr[0] = 0;
}

// ---------------- pass A: bin edges by dst>>8 into bucket-grouped intermediate (coalesced writes) ----------------
__global__ __launch_bounds__(256) void bin_edges(const int* __restrict__ src, const int* __restrict__ dst,
                                                 const float* __restrict__ ea, const int* __restrict__ row_ptr,
                                                 int* __restrict__ bfill, unsigned* __restrict__ brec,
                                                 unsigned char* __restrict__ bdst) {
    __shared__ int hist[NBUCK];
    __shared__ int lbase[NBUCK];
    __shared__ int gbase[NBUCK];
    __shared__ int cnt[NBUCK];
    __shared__ unsigned rec4[CHUNK];
    __shared__ unsigned char dl8[CHUNK];
    __shared__ unsigned char bk8[CHUNK];
    const int tid = threadIdx.x;
    const int e0 = blockIdx.x * CHUNK;
    const int n = min(NEDGES - e0, CHUNK);
    for (int i = tid; i < NBUCK; i += 256) hist[i] = 0;
    __syncthreads();
    for (int i = tid; i < n; i += 256) atomicAdd(&hist[dst[e0 + i] >> 8], 1);
    __syncthreads();
    if (tid == 0) {
        int run = 0;
        for (int b = 0; b < NBUCK; ++b) {
            lbase[b] = run;
            run += hist[b];
        }
    }
    __syncthreads();
    for (int b = tid; b < NBUCK; b += 256) {
        int h = hist[b];
        int off = h ? atomicAdd(&bfill[b], h) : 0;
        gbase[b] = row_ptr[b << 8] + off;
        cnt[b] = lbase[b];
    }
    __syncthreads();
    for (int i = tid; i < n; i += 256) {
        int d = dst[e0 + i];
        int b = d >> 8;
        int lp = atomicAdd(&cnt[b], 1);
        rec4[lp] = (unsigned)src[e0 + i] | ((unsigned)f2bf(ea[e0 + i]) << 16);
        dl8[lp] = (unsigned char)(d & 255);
        bk8[lp] = (unsigned char)b;
    }
    __syncthreads();
    for (int i = tid; i < n; i += 256) {
        int b = bk8[i];
        int pos = gbase[b] + (i - lbase[b]);
        brec[pos] = rec4[i];
        bdst[pos] = dl8[i];
    }
}

// ---------------- pass B: within-bucket counting sort; all stores confined to one block's window ----------------
__global__ __launch_bounds__(256) void sort_bucket(const unsigned* __restrict__ brec,
                                                   const unsigned char* __restrict__ bdst,
                                                   const int* __restrict__ row_ptr, unsigned* __restrict__ esrc) {
    __shared__ int rp[257];
    __shared__ int cnt[256];
    const int b = blockIdx.x;
    const int d0 = b << 8;
    const int nmax = min(256, NNODES - d0);
    const int tid = threadIdx.x;
    for (int i = tid; i <= nmax; i += 256) rp[i] = row_ptr[d0 + i];
    cnt[tid] = 0;
    __syncthreads();
    const int base = rp[0], end = rp[nmax];
    for (int i = base + tid; i < end; i += 256) {
        unsigned rec = brec[i];
        int d = bdst[i];
        int rank = atomicAdd(&cnt[d], 1);
        esrc[rp[d] + rank] = rec;
    }
}

// ---------------- input projection: h[M,128](bf16) = x[M,256] @ Wi + bi ----------------
__global__ __launch_bounds__(256) void gemm_in(const float* __restrict__ A, const unsigned short* __restrict__ Wt,
                                               const float* __restrict__ bias, unsigned* __restrict__ h32, int M) {
    __shared__ short As[128 * 128];
    const int tid = threadIdx.x;
    const int lane = tid & 63;
    const int wid = tid >> 6;
    const int row0 = blockIdx.x * 128;
    const int wr = (wid & 1) * 64;
    const int wc = (wid >> 1) * 64;
    f32x4 acc[4][4] = {};
    const int srow = tid >> 1;
    const int sk = (tid & 1) * 64;
    const int grow = min(row0 + srow, M - 1);
    for (int kt = 0; kt < 2; ++kt) {
        const float* ap = A + (size_t)grow * DIN + kt * 128 + sk;
#pragma unroll
        for (int i = 0; i < 8; ++i) {
            float4 f0 = *(const float4*)(ap + i * 8);
            float4 f1 = *(const float4*)(ap + i * 8 + 4);
            short8 s;
            s[0] = f2bf(f0.x); s[1] = f2bf(f0.y); s[2] = f2bf(f0.z); s[3] = f2bf(f0.w);
            s[4] = f2bf(f1.x); s[5] = f2bf(f1.y); s[6] = f2bf(f1.z); s[7] = f2bf(f1.w);
            int g = (sk >> 3) + i;
            *(short8*)(&As[srow * 128 + ((g ^ (srow & 7)) << 3)]) = s;
        }
        __syncthreads();
#pragma unroll
        for (int ks = 0; ks < 4; ++ks) {
            short8 a[4], b[4];
#pragma unroll
            for (int m = 0; m < 4; ++m) {
                int r = wr + m * 16 + (lane & 15);
                int g = ks * 4 + (lane >> 4);
                a[m] = *(const short8*)(&As[r * 128 + ((g ^ (r & 7)) << 3)]);
            }
#pragma unroll
            for (int n = 0; n < 4; ++n) {
                int c = wc + n * 16 + (lane & 15);
                b[n] = *(const short8*)(Wt + (size_t)c * DIN + kt * 128 + ks * 32 + (lane >> 4) * 8);
            }
#pragma unroll
            for (int m = 0; m < 4; ++m)
#pragma unroll
                for (int n = 0; n < 4; ++n)
                    acc[m][n] = __builtin_amdgcn_mfma_f32_16x16x32_bf16(a[m], b[n], acc[m][n], 0, 0, 0);
        }
        __syncthreads();
    }
    // epilogue: per-wave LDS repack (reuse As) -> coalesced uint4 stores
    float* my = ((float*)As) + wid * 1024;
    float bb[4];
#pragma unroll
    for (int n = 0; n < 4; ++n) bb[n] = bias[wc + n * 16 + (lane & 15)];
    const int rr = lane >> 2;
    const int cb = lane & 3;
#pragma unroll
    for (int m = 0; m < 4; ++m) {
#pragma unroll
        for (int n = 0; n < 4; ++n) {
            int lc = n * 16 + (lane & 15);
#pragma unroll
            for (int j = 0; j < 4; ++j) {
                int row = (lane >> 4) * 4 + j;
                my[row * 64 + (((lc >> 2) ^ (row & 7)) << 2) + (lc & 3)] = acc[m][n][j] + bb[n];
            }
        }
        float vals[16];
#pragma unroll
        for (int s = 0; s < 4; ++s) {
            int gx = (cb * 4 + s) ^ (rr & 7);
            f32x4 t4 = *(const f32x4*)(my + rr * 64 + gx * 4);
            vals[s * 4 + 0] = t4.x; vals[s * 4 + 1] = t4.y; vals[s * 4 + 2] = t4.z; vals[s * 4 + 3] = t4.w;
        }
        int grow2 = row0 + wr + m * 16 + rr;
        if (grow2 < M) {
            unsigned pk[8];
#pragma unroll
            for (int d = 0; d < 8; ++d) pk[d] = packbf(vals[2 * d], vals[2 * d + 1]);
            unsigned* op = h32 + (size_t)grow2 * 64 + (wc >> 1) + cb * 8;
            *(uint4*)op = make_uint4(pk[0], pk[1], pk[2], pk[3]);
            *(uint4*)(op + 4) = make_uint4(pk[4], pk[5], pk[6], pk[7]);
        }
    }
}

// ---------------- fused q/k/v/skip GEMM from bf16 h ----------------
__global__ __launch_bounds__(512) void gemm_qkvs(const unsigned short* __restrict__ A,
                                                 const unsigned short* __restrict__ Wt, const float* __restrict__ bq,
                                                 const float* __restrict__ bk, const float* __restrict__ bv,
                                                 const float* __restrict__ bs, unsigned* __restrict__ q32,
                                                 unsigned* __restrict__ kv, unsigned* __restrict__ xr32, int M) {
    __shared__ short As[128 * 128];
    const int tid = threadIdx.x;
    const int lane = tid & 63;
    const int wid = tid >> 6;
    const int row0 = blockIdx.x * 128;
    const int sel = wid >> 2;  // 0: q/skip, 1: k/v
    const int wr = (wid & 1) * 64;
    const int wc = ((wid >> 1) & 1) * 64;
    f32x4 acc0[4][4] = {}, acc1[4][4] = {};
    {
        const int srow = tid >> 2;
        const int sk = (tid & 3) * 32;
        const int grow = min(row0 + srow, M - 1);
        const unsigned short* ap = A + (size_t)grow * DHID + sk;
#pragma unroll
        for (int i = 0; i < 4; ++i) {
            short8 s = *(const short8*)(ap + i * 8);
            int g = (sk >> 3) + i;
            *(short8*)(&As[srow * 128 + ((g ^ (srow & 7)) << 3)]) = s;
        }
    }
    __syncthreads();
    const int b0base = sel ? 128 : 0;    // k : q
    const int b1base = sel ? 256 : 384;  // v : skip
#pragma unroll
    for (int ks = 0; ks < 4; ++ks) {
        short8 a[4], b0[4], b1[4];
#pragma unroll
        for (int m = 0; m < 4; ++m) {
            int r = wr + m * 16 + (lane & 15);
            int g = ks * 4 + (lane >> 4);
            a[m] = *(const short8*)(&As[r * 128 + ((g ^ (r & 7)) << 3)]);
        }
#pragma unroll
        for (int n = 0; n < 4; ++n) {
            int rb = wc + n * 16 + (lane & 15);
            b0[n] = *(const short8*)(Wt + (size_t)(b0base + rb) * DHID + ks * 32 + (lane >> 4) * 8);
            b1[n] = *(const short8*)(Wt + (size_t)(b1base + rb) * DHID + ks * 32 + (lane >> 4) * 8);
        }
#pragma unroll
        for (int m = 0; m < 4; ++m)
#pragma unroll
            for (int n = 0; n < 4; ++n) {
                acc0[m][n] = __builtin_amdgcn_mfma_f32_16x16x32_bf16(a[m], b0[n], acc0[m][n], 0, 0, 0);
                acc1[m][n] = __builtin_amdgcn_mfma_f32_16x16x32_bf16(a[m], b1[n], acc1[m][n], 0, 0, 0);
            }
    }
    __syncthreads();  // done reading As; reuse as repack buffer
    float* my = ((float*)As) + wid * 1024;
    const float* bias0 = sel ? bk : bq;
    const float* bias1 = sel ? bv : bs;
    float bb0[4], bb1[4];
#pragma unroll
    for (int n = 0; n < 4; ++n) {
        int c = wc + n * 16 + (lane & 15);
        bb0[n] = bias0[c];
        bb1[n] = bias1[c];
    }
    const int rr = lane >> 2;
    const int cb = lane & 3;
#pragma unroll
    for (int m = 0; m < 4; ++m) {
        float vals0[16], vals1[16];
#pragma unroll
        for (int n = 0; n < 4; ++n) {
            int lc = n * 16 + (lane & 15);
#pragma unroll
            for (int j = 0; j < 4; ++j) {
                int row = (lane >> 4) * 4 + j;
                my[row * 64 + (((lc >> 2) ^ (row & 7)) << 2) + (lc & 3)] = acc0[m][n][j] + bb0[n];
            }
        }
#pragma unroll
        for (int s = 0; s < 4; ++s) {
            int gx = (cb * 4 + s) ^ (rr & 7);
            f32x4 t4 = *(const f32x4*)(my + rr * 64 + gx * 4);
            vals0[s * 4 + 0] = t4.x; vals0[s * 4 + 1] = t4.y; vals0[s * 4 + 2] = t4.z; vals0[s * 4 + 3] = t4.w;
        }
#pragma unroll
        for (int n = 0; n < 4; ++n) {
            int lc = n * 16 + (lane & 15);
#pragma unroll
            for (int j = 0; j < 4; ++j) {
                int row = (lane >> 4) * 4 + j;
                my[row * 64 + (((lc >> 2) ^ (row & 7)) << 2) + (lc & 3)] = acc1[m][n][j] + bb1[n];
            }
        }
#pragma unroll
        for (int s = 0; s < 4; ++s) {
            int gx = (cb * 4 + s) ^ (rr & 7);
            f32x4 t4 = *(const f32x4*)(my + rr * 64 + gx * 4);
            vals1[s * 4 + 0] = t4.x; vals1[s * 4 + 1] = t4.y; vals1[s * 4 + 2] = t4.z; vals1[s * 4 + 3] = t4.w;
        }
        int grow2 = row0 + wr + m * 16 + rr;
        if (grow2 < M) {
            size_t obase = (size_t)grow2 * 64 + (wc >> 1) + cb * 8;
            if (sel == 0) {
                unsigned p0[8], p1[8];
#pragma unroll
                for (int d = 0; d < 8; ++d) {
                    p0[d] = packbf(vals0[2 * d], vals0[2 * d + 1]);
                    p1[d] = packbf(vals1[2 * d], vals1[2 * d + 1]);
                }
                *(uint4*)(q32 + obase) = make_uint4(p0[0], p0[1], p0[2], p0[3]);
                *(uint4*)(q32 + obase + 4) = make_uint4(p0[4], p0[5], p0[6], p0[7]);
                *(uint4*)(xr32 + obase) = make_uint4(p1[0], p1[1], p1[2], p1[3]);
                *(uint4*)(xr32 + obase + 4) = make_uint4(p1[4], p1[5], p1[6], p1[7]);
            } else {
                unsigned pk[8];
#pragma unroll
                for (int d = 0; d < 8; ++d) {
                    unsigned u = (unsigned)__builtin_amdgcn_cvt_pk_fp8_f32(vals0[2 * d], vals0[2 * d + 1], 0, false);
                    u = (unsigned)__builtin_amdgcn_cvt_pk_fp8_f32(vals1[2 * d], vals1[2 * d + 1], (int)u, true);
                    pk[d] = u;
                }
                *(uint4*)(kv + obase) = make_uint4(pk[0], pk[1], pk[2], pk[3]);
                *(uint4*)(kv + obase + 4) = make_uint4(pk[4], pk[5], pk[6], pk[7]);
            }
        }
    }
}

// ---------------- per-node attention + beta-gate + GELU + LayerNorm ----------------
// 4 nodes per wave: 16-lane group per node, lane owns 8 consecutive channels (4 kv dwords = 1 uint4).
// Unroll-2: two edges per group-iteration (independent exp2s, halved serial chain). Zero LDS.
// Algebra: logit = q·k + av*(q·we);  out = (Σw·v + (Σw·av)·we)/Σw. exp2-domain, defer-max.
// houtb may alias res32 (same-wave RAW only).
__global__ __launch_bounds__(256) void node_attn_fuse(const unsigned* __restrict__ q32,
                                                      const unsigned* __restrict__ kv, const unsigned* __restrict__ esrc,
                                                      const float* __restrict__ We, const int* __restrict__ row_ptr,
                                                      const unsigned* __restrict__ xr32, const unsigned* res32,
                                                      const float* __restrict__ Wb, const float* __restrict__ lng,
                                                      const float* __restrict__ lnb, unsigned* houtb, float* houtf) {
    const int tid = threadIdx.x;
    const int lane = tid & 63;
    const int lnl = lane & 15;    // lane within node group
    const int gbase = lane & 48;  // group base lane
    const int node = blockIdx.x * 16 + (tid >> 4);  // 16 nodes per block; 50000 = 3125*16 exact
    const int base = row_ptr[node], end = row_ptr[node + 1];
    const float SC = 0.25505654047688565f;  // (1/sqrt(32)) * log2(e)
    const float THR = 8.0f;

    float qv[8], wev[8];
    {
        uint4 qw = *(const uint4*)(q32 + (size_t)node * 64 + 4 * lnl);
        unsigned qd[4] = {qw.x, qw.y, qw.z, qw.w};
#pragma unroll
        for (int t = 0; t < 4; ++t) {
            qv[2 * t] = bf2f((unsigned short)qd[t]) * SC;
            qv[2 * t + 1] = bf2f((unsigned short)(qd[t] >> 16)) * SC;
        }
        float4 wlo = *(const float4*)(We + 8 * lnl);
        float4 whi = *(const float4*)(We + 8 * lnl + 4);
        wev[0] = wlo.x; wev[1] = wlo.y; wev[2] = wlo.z; wev[3] = wlo.w;
        wev[4] = whi.x; wev[5] = whi.y; wev[6] = whi.z; wev[7] = whi.w;
    }
    float qwe;
    {
        float s = 0.f;
#pragma unroll
        for (int i = 0; i < 8; ++i) s = fmaf(qv[i], wev[i], s);
        s += dpp_xor1(s);
        s += dpp_xor2(s);
        qwe = s;
    }

    float m = -1e30f, sden = 0.f, tacc = 0.f;
    float acc[8] = {};
    const unsigned* kvp = kv + 4 * lnl;

    for (int off = 0; ; off += 16) {
        int cnt = min(end - base - off, 16);  // per-group; may be <= 0
        if (__all(cnt <= 0)) break;
        unsigned u_l = 0;
        if (lnl < cnt) u_l = esrc[base + off + lnl];
        int cm = max(cnt, 0);
        cm = max(cm, __shfl_xor(cm, 16));
        cm = max(cm, __shfl_xor(cm, 32));
        // prefetch pair (0,1)
        unsigned ue0 = (unsigned)__shfl((int)u_l, gbase + 0);
        unsigned ue1 = (unsigned)__shfl((int)u_l, gbase + 1);
        uint4 kw0 = *(const uint4*)(kvp + (size_t)(ue0 & 0xFFFFu) * 64);
        uint4 kw1 = *(const uint4*)(kvp + (size_t)(ue1 & 0xFFFFu) * 64);
        for (int j = 0; j < cm; j += 2) {
            uint4 ka = kw0, kb = kw1;
            unsigned ua = ue0, ub = ue1;
            if (j + 2 < cm) {  // depth-1 pair prefetch (padding slots -> row 0, L2-hot)
                ue0 = (unsigned)__shfl((int)u_l, gbase + j + 2);
                ue1 = (unsigned)__shfl((int)u_l, gbase + j + 3);
                kw0 = *(const uint4*)(kvp + (size_t)(ue0 & 0xFFFFu) * 64);
                kw1 = *(const uint4*)(kvp + (size_t)(ue1 & 0xFFFFu) * 64);
            }
            float av0 = bf2f((unsigned short)(ua >> 16));
            float av1 = bf2f((unsigned short)(ub >> 16));
            unsigned kd0[4] = {ka.x, ka.y, ka.z, ka.w};
            unsigned kd1[4] = {kb.x, kb.y, kb.z, kb.w};
            float vj0[8], vj1[8];
            float p0 = 0.f, p1 = 0.f;
#pragma unroll
            for (int t = 0; t < 4; ++t) {
                f32x2 k0 = __builtin_amdgcn_cvt_pk_f32_fp8((int)kd0[t], false);
                f32x2 v0 = __builtin_amdgcn_cvt_pk_f32_fp8((int)kd0[t], true);
                f32x2 k1 = __builtin_amdgcn_cvt_pk_f32_fp8((int)kd1[t], false);
                f32x2 v1 = __builtin_amdgcn_cvt_pk_f32_fp8((int)kd1[t], true);
                p0 = fmaf(qv[2 * t], k0.x, p0);
                p0 = fmaf(qv[2 * t + 1], k0.y, p0);
                p1 = fmaf(qv[2 * t], k1.x, p1);
                p1 = fmaf(qv[2 * t + 1], k1.y, p1);
                vj0[2 * t] = v0.x; vj0[2 * t + 1] = v0.y;
                vj1[2 * t] = v1.x; vj1[2 * t + 1] = v1.y;
            }
            p0 += dpp_xor1(p0);
            p0 += dpp_xor2(p0);
            p1 += dpp_xor1(p1);
            p1 += dpp_xor2(p1);
            p0 = fmaf(av0, qwe, p0);
            p1 = fmaf(av1, qwe, p1);
            p0 = (j < cnt) ? p0 : -3e38f;
            p1 = (j + 1 < cnt) ? p1 : -3e38f;
            float pm = fmaxf(p0, p1);
            if (__any(pm - m > THR)) {  // rare: max update + rescale (taken on first pair)
                float mn2 = fmaxf(m, pm);
                float sc = exp2f(m - mn2);
                float w0 = exp2f(p0 - mn2), w1 = exp2f(p1 - mn2);
                sden = fmaf(sden, sc, w0 + w1);
                tacc = fmaf(tacc, sc, fmaf(w0, av0, w1 * av1));
#pragma unroll
                for (int i = 0; i < 8; ++i) acc[i] = fmaf(acc[i], sc, fmaf(w0, vj0[i], w1 * vj1[i]));
                m = mn2;
            } else {  // common path: independent exp2s, 2-deep fma tree
                float w0 = exp2f(p0 - m), w1 = exp2f(p1 - m);
                sden += w0 + w1;
                tacc = fmaf(w0, av0, fmaf(w1, av1, tacc));
#pragma unroll
                for (int i = 0; i < 8; ++i) acc[i] = fmaf(w0, vj0[i], fmaf(w1, vj1[i], acc[i]));
            }
        }
    }

    float rden = 1.f / (sden + 1e-16f);
    float o[8];
#pragma unroll
    for (int i = 0; i < 8; ++i) o[i] = fmaf(tacc, wev[i], acc[i]) * rden;

    // ---- fused epilogue in the same 8-ch/lane layout (reduces within 16-lane group) ----
    float x[8];
    {
        uint4 xw = *(const uint4*)(xr32 + (size_t)node * 64 + 4 * lnl);
        unsigned xd[4] = {xw.x, xw.y, xw.z, xw.w};
#pragma unroll
        for (int t = 0; t < 4; ++t) {
            x[2 * t] = bf2f((unsigned short)xd[t]);
            x[2 * t + 1] = bf2f((unsigned short)(xd[t] >> 16));
        }
    }
    float bl = 0.f;
#pragma unroll
    for (int t = 0; t < 2; ++t) {
        float4 w0 = *(const float4*)(Wb + 8 * lnl + 4 * t);
        float4 w1 = *(const float4*)(Wb + 128 + 8 * lnl + 4 * t);
        float4 w2 = *(const float4*)(Wb + 256 + 8 * lnl + 4 * t);
        bl = fmaf(o[4 * t], w0.x, bl); bl = fmaf(o[4 * t + 1], w0.y, bl);
        bl = fmaf(o[4 * t + 2], w0.z, bl); bl = fmaf(o[4 * t + 3], w0.w, bl);
        bl = fmaf(x[4 * t], w1.x, bl); bl = fmaf(x[4 * t + 1], w1.y, bl);
        bl = fmaf(x[4 * t + 2], w1.z, bl); bl = fmaf(x[4 * t + 3], w1.w, bl);
        bl = fmaf(o[4 * t] - x[4 * t], w2.x, bl); bl = fmaf(o[4 * t + 1] - x[4 * t + 1], w2.y, bl);
        bl = fmaf(o[4 * t + 2] - x[4 * t + 2], w2.z, bl); bl = fmaf(o[4 * t + 3] - x[4 * t + 3], w2.w, bl);
    }
    bl = red16(bl);
    float beta = 1.f / (1.f + __expf(-bl));
    float tpre[8];
    {
        uint4 rw = *(const uint4*)(res32 + (size_t)node * 64 + 4 * lnl);
        unsigned rd[4] = {rw.x, rw.y, rw.z, rw.w};
#pragma unroll
        for (int i = 0; i < 8; ++i) {
            float gg = beta * x[i] + (1.f - beta) * o[i];
            gg = 0.5f * gg * (1.f + erff(gg * 0.70710678118654752f));
            float rv = (i & 1) ? bf2f((unsigned short)(rd[i >> 1] >> 16)) : bf2f((unsigned short)rd[i >> 1]);
            tpre[i] = gg + rv;
        }
    }
    float su = 0.f, sq = 0.f;
#pragma unroll
    for (int i = 0; i < 8; ++i) {
        su += tpre[i];
        sq = fmaf(tpre[i], tpre[i], sq);
    }
    su = red16(su);
    sq = red16(sq);
    float mu = su * (1.f / 128.f);
    float var = sq * (1.f / 128.f) - mu * mu;
    float inv = rsqrtf(var + 1e-5f);
    float4 g0 = *(const float4*)(lng + 8 * lnl);
    float4 g1 = *(const float4*)(lng + 8 * lnl + 4);
    float4 b0 = *(const float4*)(lnb + 8 * lnl);
    float4 b1 = *(const float4*)(lnb + 8 * lnl + 4);
    float gg[8] = {g0.x, g0.y, g0.z, g0.w, g1.x, g1.y, g1.z, g1.w};
    float bb[8] = {b0.x, b0.y, b0.z, b0.w, b1.x, b1.y, b1.z, b1.w};
    float ov[8];
#pragma unroll
    for (int i = 0; i < 8; ++i) ov[i] = (tpre[i] - mu) * inv * gg[i] + bb[i];
    if (houtf) {
        float* op = houtf + (size_t)node * 128 + 8 * lnl;
        *(float4*)op = make_float4(ov[0], ov[1], ov[2], ov[3]);
        *(float4*)(op + 4) = make_float4(ov[4], ov[5], ov[6], ov[7]);
    } else {
        unsigned pk[4];
#pragma unroll
        for (int d = 0; d < 4; ++d) pk[d] = packbf(ov[2 * d], ov[2 * d + 1]);
        *(uint4*)(houtb + (size_t)node * 64 + 4 * lnl) = make_uint4(pk[0], pk[1], pk[2], pk[3]);
    }
}

extern "C" void kernel_launch(void* const* d_in, const int* in_sizes, int n_in, void* d_out, int out_size,
                              void* d_ws, size_t ws_size, hipStream_t stream) {
    const float* x = (const float*)d_in[0];
    const int* ei = (const int*)d_in[1];
    const float* ea = (const float*)d_in[2];
    const float* Wi = (const float*)d_in[3];
    const float* bi = (const float*)d_in[4];
    const float* Wq = (const float*)d_in[5];
    const float* bq = (const float*)d_in[6];
    const float* Wk = (const float*)d_in[7];
    const float* bk = (const float*)d_in[8];
    const float* Wv = (const float*)d_in[9];
    const float* bv = (const float*)d_in[10];
    const float* We = (const float*)d_in[11];
    const float* Wskip = (const float*)d_in[12];
    const float* bskip = (const float*)d_in[13];
    const float* Wbeta = (const float*)d_in[14];
    const float* lng = (const float*)d_in[15];
    const float* lnb = (const float*)d_in[16];

    const int* srcp = ei;
    const int* dstp = ei + NEDGES;

    char* p = (char*)d_ws;
    auto alloc = [&](size_t bytes) {
        void* r = (void*)p;
        p += (bytes + 255) & ~(size_t)255;
        return r;
    };
    unsigned* h32 = (unsigned*)alloc((size_t)NNODES * 64 * 4);
    unsigned* q32 = (unsigned*)alloc((size_t)NNODES * 64 * 4);
    unsigned* xr32 = (unsigned*)alloc((size_t)NNODES * 64 * 4);
    unsigned* kv = (unsigned*)alloc((size_t)NNODES * 64 * 4);
    unsigned short* Wit = (unsigned short*)alloc((size_t)DHID * DIN * 2);
    unsigned short* Wt3 = (unsigned short*)alloc((size_t)3 * 512 * DHID * 2);
    int* counts = (int*)alloc((size_t)(NNODES + 256) * 4);  // counts + bucket fill (contiguous, one memset)
    int* bfill = counts + NNODES;
    int* row_ptr = (int*)alloc((size_t)(NNODES + 1) * 4);
    unsigned* esrc = (unsigned*)alloc((size_t)NEDGES * 4);
    unsigned* brec = (unsigned*)alloc((size_t)NEDGES * 4);
    unsigned char* bdst = (unsigned char*)alloc((size_t)NEDGES);
    int* partials = (int*)alloc(256 * 4);

    const int EB = (NEDGES + 255) / 256;  // 3125
    const int NB = (NNODES + 255) / 256;  // 196
    const int WB = NNODES / 16;           // 3125
    const int PB = (DHID * DIN + 3 * 512 * DHID + 255) / 256;  // 896
    const int AB = (NEDGES + CHUNK - 1) / CHUNK;  // 196

    hipMemsetAsync(counts, 0, (size_t)(NNODES + 256) * 4, stream);
    prep_hist<<<PB + EB, 256, 0, stream>>>(Wi, Wq, Wk, Wv, Wskip, Wit, Wt3, dstp, counts, PB);
    gemm_in<<<GBLK, 256, 0, stream>>>(x, Wit, bi, h32, NNODES);
    k_scan_block<<<NB, 256, 0, stream>>>(counts, row_ptr + 1, partials, NNODES);
    k_apply2<<<NB, 256, 0, stream>>>(partials, row_ptr, NNODES, NB);
    bin_edges<<<AB, 256, 0, stream>>>(srcp, dstp, ea, row_ptr, bfill, brec, bdst);
    sort_bucket<<<NBUCK, 256, 0, stream>>>(brec, bdst, row_ptr, esrc);

    for (int l = 0; l < 3; ++l) {
        const size_t bo = (size_t)l * 128;
        gemm_qkvs<<<GBLK, 512, 0, stream>>>((const unsigned short*)h32, Wt3 + (size_t)l * 512 * DHID, bq + bo, bk + bo,
                                            bv + bo, bskip + bo, q32, kv, xr32, NNODES);
        node_attn_fuse<<<WB, 256, 0, stream>>>(q32, kv, esrc, We + bo, row_ptr, xr32, h32,
                                               Wbeta + (size_t)l * 384, lng + bo, lnb + bo, h32,
                                               (l == 2) ? (float*)d_out : nullptr);
    }
}